// Round 5
// baseline (2303.520 us; speedup 1.0000x reference)
//
#include <hip/hip_runtime.h>
#include <math.h>

#define L 200
#define H 128
#define HD 64
#define NB 2
#define BTOT 2048
#define HH (H * H)
#define XST 136   // Xs/F1 row stride (shorts): 272B, 16B-aligned
#define QST 68    // Qs/Ks row stride (shorts): 136B, 8B-aligned (b64 reads)
#define VST 264   // Vt row stride (shorts)

typedef short bf16x8 __attribute__((ext_vector_type(8)));
typedef short bf16x4 __attribute__((ext_vector_type(4)));
typedef float f32x4 __attribute__((ext_vector_type(4)));
typedef unsigned short u16;

#define MFMA16 __builtin_amdgcn_mfma_f32_16x16x32_bf16

// ---------- helpers ----------
__device__ __forceinline__ u16 f2bf(float f) {
    unsigned u = __builtin_bit_cast(unsigned, f);
    u = u + 0x7fffu + ((u >> 16) & 1u);
    return (u16)(u >> 16);
}
__device__ __forceinline__ float bf2f(u16 s) {
    return __builtin_bit_cast(float, ((unsigned)s) << 16);
}
__device__ __forceinline__ bf16x8 pack8(float4 a, float4 b, float sc) {
    bf16x8 r;
    r[0] = (short)f2bf(a.x * sc); r[1] = (short)f2bf(a.y * sc);
    r[2] = (short)f2bf(a.z * sc); r[3] = (short)f2bf(a.w * sc);
    r[4] = (short)f2bf(b.x * sc); r[5] = (short)f2bf(b.y * sc);
    r[6] = (short)f2bf(b.z * sc); r[7] = (short)f2bf(b.w * sc);
    return r;
}
// two ds_read_b64 (stride 136B is only 8B-aligned)
__device__ __forceinline__ bf16x8 ld_q8(const u16* p) {
    bf16x4 lo = *(const bf16x4*)p;
    bf16x4 hi = *(const bf16x4*)(p + 4);
    bf16x8 r;
    r[0] = lo[0]; r[1] = lo[1]; r[2] = lo[2]; r[3] = lo[3];
    r[4] = hi[0]; r[5] = hi[1]; r[6] = hi[2]; r[7] = hi[3];
    return r;
}
__device__ __forceinline__ float rsum16(float v) {
    v += __shfl_xor(v, 1); v += __shfl_xor(v, 2);
    v += __shfl_xor(v, 4); v += __shfl_xor(v, 8);
    return v;
}

// ---------- weight f32 -> bf16 ----------
__global__ __launch_bounds__(256) void cvt_kernel(const float* __restrict__ src,
                                                  u16* __restrict__ dst, int n8) {
    int i = blockIdx.x * 256 + threadIdx.x;
    if (i >= n8) return;
    float4 a0 = ((const float4*)src)[i * 2];
    float4 a1 = ((const float4*)src)[i * 2 + 1];
    ((bf16x8*)dst)[i] = pack8(a0, a1, 1.0f);
}

// ---------- persistent per-sequence kernel: one block per sequence ----------
__global__ __launch_bounds__(512, 1) void sasrec_kernel(
        const int* __restrict__ log_seqs, const int* __restrict__ pid, const int* __restrict__ nid,
        const float* __restrict__ item, const float* __restrict__ post,
        const u16* __restrict__ w16,
        const float* __restrict__ qb, const float* __restrict__ kb, const float* __restrict__ vb,
        const float* __restrict__ ob, const float* __restrict__ b1, const float* __restrict__ b2,
        const float* __restrict__ ln1g, const float* __restrict__ ln1b,
        const float* __restrict__ ln2g, const float* __restrict__ ln2b,
        const float* __restrict__ lnfg, const float* __restrict__ lnfb,
        float* __restrict__ out) {
    __shared__ u16 lds[73472];              // 146,944 B
    u16* Xs = lds;                          // [208][136]
    u16* Qs = lds + 28288;                  // [208][68]
    u16* Ks = lds + 42432;                  // [208][68]
    u16* Vt = lds + 56576;                  // [64][264]
    u16* F1 = Qs;                           // [208][136] reuses Qs+Ks after attn

    const int b = blockIdx.x;
    const int tid = threadIdx.x;
    const int w = tid >> 6, lane = tid & 63, g = lane >> 4, l15 = lane & 15;
    const int rp = 8 * (l15 >> 2) + (l15 & 3);
    const f32x4 czero = {0.f, 0.f, 0.f, 0.f};
    const bf16x8 zfrag = {0, 0, 0, 0, 0, 0, 0, 0};

    // ---- embed: Xs = item[id]*sqrt(H) + pos; rows 200..207 zeroed ----
    {
        const int* ids = log_seqs + (size_t)b * L;
        int q = tid & 3;
        const float sc = 11.313708498984761f;
#pragma unroll
        for (int half = 0; half < 2; ++half) {
            int r = half * 128 + (tid >> 2);
            if (r < 200) {
                int id = ids[r];
                int p = id ? (r + 1) : 0;
                const float4* irow = (const float4*)item + (size_t)id * 32 + q * 8;
                const float4* prow = (const float4*)post + (size_t)p * 32 + q * 8;
#pragma unroll
                for (int i = 0; i < 4; ++i) {
                    float4 a0 = irow[2 * i], a1 = irow[2 * i + 1];
                    float4 p0 = prow[2 * i], p1 = prow[2 * i + 1];
                    float4 o0 = make_float4(a0.x * sc + p0.x, a0.y * sc + p0.y,
                                            a0.z * sc + p0.z, a0.w * sc + p0.w);
                    float4 o1 = make_float4(a1.x * sc + p1.x, a1.y * sc + p1.y,
                                            a1.z * sc + p1.z, a1.w * sc + p1.w);
                    *(bf16x8*)&Xs[r * XST + q * 32 + i * 8] = pack8(o0, o1, 1.0f);
                }
            } else if (r < 208) {
#pragma unroll
                for (int i = 0; i < 4; ++i)
                    *(bf16x8*)&Xs[r * XST + q * 32 + i * 8] = zfrag;
            }
        }
        // zero Vt cols 208..263 once (never written; avoids NaN*0 in PV MFMA)
        for (int idx = tid; idx < 64 * 56; idx += 512)
            Vt[(idx / 56) * VST + 208 + idx % 56] = 0;
    }
    __syncthreads();

    const int nrt = (w <= 4) ? 2 : 1;
    const int rt0 = w, rt1 = w + 8;
    const int ta = (w < 7) ? (12 - w) : -1;
    const int tb = (w >= 1 && w < 7) ? (w - 1) : -1;

    for (int layer = 0; layer < NB; ++layer) {
        const u16* Wq = w16 + (size_t)(0 * NB + layer) * HH;
        const u16* Wk = w16 + (size_t)(1 * NB + layer) * HH;
        const u16* Wv = w16 + (size_t)(2 * NB + layer) * HH;
        const u16* Wo = w16 + (size_t)(3 * NB + layer) * HH;
        const u16* W1 = w16 + (size_t)(4 * NB + layer) * HH;
        const u16* W2 = w16 + (size_t)(5 * NB + layer) * HH;

        f32x4 mha[2][8];
#pragma unroll
        for (int ct = 0; ct < 8; ++ct) {
            float bv = ob[layer * H + ct * 16 + l15];
            mha[0][ct] = (f32x4){bv, bv, bv, bv};
            mha[1][ct] = mha[0][ct];
        }

        for (int h = 0; h < 2; ++h) {
            // ---- QKV for head h: 39 units = 13 row-tiles x {Q,K,V} ----
            for (int u = w; u < 39; u += 8) {
                int rt = u / 3;
                int mat = u - rt * 3;
                int arow = rt * 16 + l15;
                bf16x8 xa[4];
#pragma unroll
                for (int kc = 0; kc < 4; ++kc)
                    xa[kc] = *(const bf16x8*)&Xs[arow * XST + kc * 32 + g * 8];
                if (mat == 2) {
                    // V with swapped operands -> writes V^T directly
                    f32x4 acc[4];
#pragma unroll
                    for (int dt = 0; dt < 4; ++dt) {
                        float4 bv4 = *(const float4*)&vb[layer * H + h * 64 + dt * 16 + g * 4];
                        acc[dt] = (f32x4){bv4.x, bv4.y, bv4.z, bv4.w};
                    }
#pragma unroll
                    for (int kc = 0; kc < 4; ++kc)
#pragma unroll
                        for (int dt = 0; dt < 4; ++dt) {
                            bf16x8 wa = *(const bf16x8*)(Wv + (size_t)(h * 64 + dt * 16 + l15) * H + kc * 32 + g * 8);
                            acc[dt] = MFMA16(wa, xa[kc], acc[dt], 0, 0, 0);
                        }
#pragma unroll
                    for (int dt = 0; dt < 4; ++dt)
#pragma unroll
                        for (int r = 0; r < 4; ++r)
                            Vt[(dt * 16 + g * 4 + r) * VST + rt * 16 + l15] = f2bf(acc[dt][r]);
                } else {
                    const u16* Wm = mat ? Wk : Wq;
                    const float* bm = mat ? (kb + layer * H) : (qb + layer * H);
                    u16* dst = mat ? Ks : Qs;
                    float scale = mat ? 1.0f : 0.125f;
                    f32x4 acc[4];
#pragma unroll
                    for (int ct = 0; ct < 4; ++ct) {
                        float bv = bm[h * 64 + ct * 16 + l15];
                        acc[ct] = (f32x4){bv, bv, bv, bv};
                    }
#pragma unroll
                    for (int kc = 0; kc < 4; ++kc)
#pragma unroll
                        for (int ct = 0; ct < 4; ++ct) {
                            bf16x8 wb = *(const bf16x8*)(Wm + (size_t)(h * 64 + ct * 16 + l15) * H + kc * 32 + g * 8);
                            acc[ct] = MFMA16(xa[kc], wb, acc[ct], 0, 0, 0);
                        }
#pragma unroll
                    for (int ct = 0; ct < 4; ++ct)
#pragma unroll
                        for (int r = 0; r < 4; ++r)
                            dst[(rt * 16 + g * 4 + r) * QST + ct * 16 + l15] = f2bf(acc[ct][r] * scale);
                }
            }
            __syncthreads();

            // ---- attention (tiles pair-balanced; wave 7 idle) ----
            f32x4 o2[2][4];
            float lr2[2];
#pragma unroll
            for (int ti = 0; ti < 2; ++ti) {
                int qt = ti ? tb : ta;
                lr2[ti] = 1.f;
#pragma unroll
                for (int md = 0; md < 4; ++md) o2[ti][md] = czero;
                if (qt < 0) continue;
                int qrow = qt * 16 + l15;
                bf16x8 qf0 = ld_q8(&Qs[qrow * QST + g * 8]);
                bf16x8 qf1 = ld_q8(&Qs[qrow * QST + 32 + g * 8]);
                float mr = -1e30f, lr = 0.f;
                int kcmax = qt >> 2;
                for (int kc = 0; kc <= kcmax; ++kc) {
                    int kbase = kc * 64;
                    f32x4 c[4];
#pragma unroll
                    for (int mt = 0; mt < 4; ++mt) {
                        int krow = kbase + (mt >> 1) * 32 + (mt & 1) * 4 + rp;
                        krow = min(krow, 207);
                        bf16x8 ka0 = ld_q8(&Ks[krow * QST + g * 8]);
                        bf16x8 ka1 = ld_q8(&Ks[krow * QST + 32 + g * 8]);
                        c[mt] = MFMA16(ka0, qf0, czero, 0, 0, 0);
                        c[mt] = MFMA16(ka1, qf1, c[mt], 0, 0, 0);
                    }
                    float pm = -1e30f;
#pragma unroll
                    for (int mt = 0; mt < 4; ++mt)
#pragma unroll
                        for (int r = 0; r < 4; ++r) {
                            int kact = kbase + 32 * (mt >> 1) + 4 * (mt & 1) + 8 * g + r;
                            float s = (kact <= qrow) ? c[mt][r] : -1e30f;
                            c[mt][r] = s;
                            pm = fmaxf(pm, s);
                        }
                    pm = fmaxf(pm, __shfl_xor(pm, 16));
                    pm = fmaxf(pm, __shfl_xor(pm, 32));
                    float mnew = fmaxf(mr, pm);
                    float sf = __expf(mr - mnew);
                    mr = mnew;
                    float ps = 0.f;
#pragma unroll
                    for (int mt = 0; mt < 4; ++mt)
#pragma unroll
                        for (int r = 0; r < 4; ++r) {
                            float p = __expf(c[mt][r] - mnew);
                            c[mt][r] = p;
                            ps += p;
                        }
                    ps += __shfl_xor(ps, 16);
                    ps += __shfl_xor(ps, 32);
                    lr = lr * sf + ps;
#pragma unroll
                    for (int md = 0; md < 4; ++md)
#pragma unroll
                        for (int r = 0; r < 4; ++r) o2[ti][md][r] *= sf;
#pragma unroll
                    for (int ks = 0; ks < 2; ++ks) {
                        bf16x8 pb;
#pragma unroll
                        for (int j = 0; j < 8; ++j)
                            pb[j] = (short)f2bf(c[2 * ks + (j >> 2)][j & 3]);
#pragma unroll
                        for (int md = 0; md < 4; ++md) {
                            bf16x8 va = *(const bf16x8*)&Vt[(md * 16 + l15) * VST + kbase + ks * 32 + g * 8];
                            o2[ti][md] = MFMA16(va, pb, o2[ti][md], 0, 0, 0);
                        }
                    }
                }
                lr2[ti] = lr;
            }
            __syncthreads();
            // ---- write O (normalized) into Qs ----
#pragma unroll
            for (int ti = 0; ti < 2; ++ti) {
                int qt = ti ? tb : ta;
                if (qt < 0) continue;
                float inv = 1.0f / lr2[ti];
#pragma unroll
                for (int md = 0; md < 4; ++md)
#pragma unroll
                    for (int r = 0; r < 4; ++r)
                        Qs[(qt * 16 + l15) * QST + md * 16 + g * 4 + r] = f2bf(o2[ti][md][r] * inv);
            }
            __syncthreads();
            // ---- O-proj partial accumulate (head h) ----
            for (int r2 = 0; r2 < nrt; ++r2) {
                int rt = r2 ? rt1 : rt0;
#pragma unroll
                for (int kc2 = 0; kc2 < 2; ++kc2) {
                    bf16x8 af = ld_q8(&Qs[(rt * 16 + l15) * QST + kc2 * 32 + g * 8]);
#pragma unroll
                    for (int ct = 0; ct < 8; ++ct) {
                        bf16x8 wb = *(const bf16x8*)(Wo + (size_t)(ct * 16 + l15) * H + h * 64 + kc2 * 32 + g * 8);
                        mha[r2][ct] = MFMA16(af, wb, mha[r2][ct], 0, 0, 0);
                    }
                }
            }
            __syncthreads();
        }  // heads

        // ---- residual + LN1 -> Xs (two-phase) ----
        unsigned lnres[2][4][4];
        {
            float gg[8], bb[8];
#pragma unroll
            for (int ct = 0; ct < 8; ++ct) {
                gg[ct] = ln1g[layer * H + ct * 16 + l15];
                bb[ct] = ln1b[layer * H + ct * 16 + l15];
            }
            for (int r2 = 0; r2 < nrt; ++r2) {
                int rt = r2 ? rt1 : rt0;
#pragma unroll
                for (int r = 0; r < 4; ++r) {
                    int row = rt * 16 + g * 4 + r;
                    float v[8];
                    float s = 0.f;
#pragma unroll
                    for (int ct = 0; ct < 8; ++ct) {
                        v[ct] = mha[r2][ct][r] + bf2f(Xs[row * XST + ct * 16 + l15]);
                        s += v[ct];
                    }
                    float mean = rsum16(s) * 0.0078125f;
                    float s2 = 0.f;
#pragma unroll
                    for (int ct = 0; ct < 8; ++ct) { float d = v[ct] - mean; s2 += d * d; }
                    float inv = rsqrtf(rsum16(s2) * 0.0078125f + 1e-8f);
                    bool zg = (row >= 200);
#pragma unroll
                    for (int cp = 0; cp < 4; ++cp) {
                        float v0 = (v[2 * cp] - mean) * inv * gg[2 * cp] + bb[2 * cp];
                        float v1 = (v[2 * cp + 1] - mean) * inv * gg[2 * cp + 1] + bb[2 * cp + 1];
                        u16 lo = zg ? (u16)0 : f2bf(v0);
                        u16 hi = zg ? (u16)0 : f2bf(v1);
                        lnres[r2][r][cp] = (unsigned)lo | ((unsigned)hi << 16);
                    }
                }
            }
        }
        __syncthreads();
        for (int r2 = 0; r2 < nrt; ++r2) {
            int rt = r2 ? rt1 : rt0;
#pragma unroll
            for (int r = 0; r < 4; ++r) {
                int row = rt * 16 + g * 4 + r;
#pragma unroll
                for (int cp = 0; cp < 4; ++cp) {
                    Xs[row * XST + (2 * cp) * 16 + l15] = (u16)lnres[r2][r][cp];
                    Xs[row * XST + (2 * cp + 1) * 16 + l15] = (u16)(lnres[r2][r][cp] >> 16);
                }
            }
        }
        __syncthreads();

        // ---- FFN1 -> F1 (pool) ----
        for (int r2 = 0; r2 < nrt; ++r2) {
            int rt = r2 ? rt1 : rt0;
            int arow = rt * 16 + l15;
            bf16x8 xa[4];
#pragma unroll
            for (int kc = 0; kc < 4; ++kc)
                xa[kc] = *(const bf16x8*)&Xs[arow * XST + kc * 32 + g * 8];
            f32x4 acc[8];
#pragma unroll
            for (int ct = 0; ct < 8; ++ct) {
                float bv = b1[layer * H + ct * 16 + l15];
                acc[ct] = (f32x4){bv, bv, bv, bv};
            }
#pragma unroll
            for (int kc = 0; kc < 4; ++kc)
#pragma unroll
                for (int ct = 0; ct < 8; ++ct) {
                    bf16x8 wb = *(const bf16x8*)(W1 + (size_t)(ct * 16 + l15) * H + kc * 32 + g * 8);
                    acc[ct] = MFMA16(xa[kc], wb, acc[ct], 0, 0, 0);
                }
#pragma unroll
            for (int ct = 0; ct < 8; ++ct)
#pragma unroll
                for (int r = 0; r < 4; ++r)
                    F1[(rt * 16 + g * 4 + r) * XST + ct * 16 + l15] = f2bf(fmaxf(acc[ct][r], 0.f));
        }
        __syncthreads();

        // ---- FFN2 + residual + LN2 (+ final LN + logits on last layer) ----
        {
            float gg[8], bb[8], gf[8], bf2[8];
#pragma unroll
            for (int ct = 0; ct < 8; ++ct) {
                gg[ct] = ln2g[layer * H + ct * 16 + l15];
                bb[ct] = ln2b[layer * H + ct * 16 + l15];
                gf[ct] = lnfg[ct * 16 + l15];
                bf2[ct] = lnfb[ct * 16 + l15];
            }
            for (int r2 = 0; r2 < nrt; ++r2) {
                int rt = r2 ? rt1 : rt0;
                int arow = rt * 16 + l15;
                bf16x8 xa[4];
#pragma unroll
                for (int kc = 0; kc < 4; ++kc)
                    xa[kc] = *(const bf16x8*)&F1[arow * XST + kc * 32 + g * 8];
                f32x4 acc[8];
#pragma unroll
                for (int ct = 0; ct < 8; ++ct) {
                    float bv = b2[layer * H + ct * 16 + l15];
                    acc[ct] = (f32x4){bv, bv, bv, bv};
                }
#pragma unroll
                for (int kc = 0; kc < 4; ++kc)
#pragma unroll
                    for (int ct = 0; ct < 8; ++ct) {
                        bf16x8 wb = *(const bf16x8*)(W2 + (size_t)(ct * 16 + l15) * H + kc * 32 + g * 8);
                        acc[ct] = MFMA16(xa[kc], wb, acc[ct], 0, 0, 0);
                    }
#pragma unroll
                for (int r = 0; r < 4; ++r) {
                    int row = rt * 16 + g * 4 + r;
                    float v[8];
                    float s = 0.f;
#pragma unroll
                    for (int ct = 0; ct < 8; ++ct) {
                        v[ct] = acc[ct][r] + bf2f(Xs[row * XST + ct * 16 + l15]);
                        s += v[ct];
                    }
                    float mean = rsum16(s) * 0.0078125f;
                    float s2 = 0.f;
#pragma unroll
                    for (int ct = 0; ct < 8; ++ct) { float d = v[ct] - mean; s2 += d * d; }
                    float inv = rsqrtf(rsum16(s2) * 0.0078125f + 1e-8f);
#pragma unroll
                    for (int ct = 0; ct < 8; ++ct) v[ct] = (v[ct] - mean) * inv * gg[ct] + bb[ct];
                    if (layer == 0) {
                        bool zg = (row >= 200);
#pragma unroll
                        for (int cp = 0; cp < 4; ++cp) {
                            u16 lo = zg ? (u16)0 : f2bf(v[2 * cp]);
                            u16 hi = zg ? (u16)0 : f2bf(v[2 * cp + 1]);
                            lnres[r2][r][cp] = (unsigned)lo | ((unsigned)hi << 16);
                        }
                    } else {
                        // final LN
                        float t = 0.f;
#pragma unroll
                        for (int ct = 0; ct < 8; ++ct) t += v[ct];
                        float mean2 = rsum16(t) * 0.0078125f;
                        float t2 = 0.f;
#pragma unroll
                        for (int ct = 0; ct < 8; ++ct) { float d = v[ct] - mean2; t2 += d * d; }
                        float inv2 = rsqrtf(rsum16(t2) * 0.0078125f + 1e-8f);
#pragma unroll
                        for (int ct = 0; ct < 8; ++ct) v[ct] = (v[ct] - mean2) * inv2 * gf[ct] + bf2[ct];
                        if (row < 200) {
                            int gr = b * L + row;
                            const float* prow = item + (size_t)pid[gr] * H;
                            const float* nrow = item + (size_t)nid[gr] * H;
                            float sp = 0.f, sn = 0.f;
#pragma unroll
                            for (int ct = 0; ct < 8; ++ct) {
                                sp += v[ct] * prow[ct * 16 + l15];
                                sn += v[ct] * nrow[ct * 16 + l15];
                            }
                            sp = rsum16(sp);
                            sn = rsum16(sn);
                            if (l15 == 0) {
                                out[gr] = sp;
                                out[(size_t)BTOT * L + gr] = sn;
                            }
                        }
                    }
                }
            }
        }
        if (layer == 0) {
            __syncthreads();
            for (int r2 = 0; r2 < nrt; ++r2) {
                int rt = r2 ? rt1 : rt0;
#pragma unroll
                for (int r = 0; r < 4; ++r) {
                    int row = rt * 16 + g * 4 + r;
#pragma unroll
                    for (int cp = 0; cp < 4; ++cp) {
                        Xs[row * XST + (2 * cp) * 16 + l15] = (u16)lnres[r2][r][cp];
                        Xs[row * XST + (2 * cp + 1) * 16 + l15] = (u16)(lnres[r2][r][cp] >> 16);
                    }
                }
            }
            __syncthreads();
        }
    }  // layers
}

extern "C" void kernel_launch(void* const* d_in, const int* in_sizes, int n_in,
                              void* d_out, int out_size, void* d_ws, size_t ws_size,
                              hipStream_t stream) {
    const int* log_seqs = (const int*)d_in[1];
    const int* pos_seqs = (const int*)d_in[2];
    const int* neg_seqs = (const int*)d_in[3];
    const float* item = (const float*)d_in[4];
    const float* post = (const float*)d_in[5];
    const float* qw = (const float*)d_in[6];
    const float* kw = (const float*)d_in[7];
    const float* vw = (const float*)d_in[8];
    const float* ow = (const float*)d_in[9];
    const float* qb = (const float*)d_in[10];
    const float* kb = (const float*)d_in[11];
    const float* vb = (const float*)d_in[12];
    const float* ob = (const float*)d_in[13];
    const float* w1 = (const float*)d_in[14];
    const float* b1 = (const float*)d_in[15];
    const float* w2 = (const float*)d_in[16];
    const float* b2 = (const float*)d_in[17];
    const float* ln1g = (const float*)d_in[18];
    const float* ln1b = (const float*)d_in[19];
    const float* ln2g = (const float*)d_in[20];
    const float* ln2b = (const float*)d_in[21];
    const float* lnfg = (const float*)d_in[22];
    const float* lnfb = (const float*)d_in[23];
    float* out = (float*)d_out;

    u16* w16 = (u16*)d_ws;  // 12 * 128*128 bf16 = 393 KB

    const float* wsrc[6] = {qw, kw, vw, ow, w1, w2};
    int n8 = NB * HH / 8;
    for (int t = 0; t < 6; ++t)
        cvt_kernel<<<(n8 + 255) / 256, 256, 0, stream>>>(wsrc[t], w16 + (size_t)t * NB * HH, n8);

    sasrec_kernel<<<BTOT, 512, 0, stream>>>(log_seqs, pos_seqs, neg_seqs, item, post, w16,
                                            qb, kb, vb, ob, b1, b2,
                                            ln1g, ln1b, ln2g, ln2b, lnfg, lnfb, out);
}

// Round 8
// 1760.993 us; speedup vs baseline: 1.3081x; 1.3081x over previous
//
#include <hip/hip_runtime.h>
#include <math.h>

#define L 200
#define H 128
#define HD 64
#define NB 2
#define BTOT 2048
#define HH (H * H)
#define XSS 136   // LDS row stride in shorts (272B, 16B-aligned)

typedef short bf16x8 __attribute__((ext_vector_type(8)));
typedef short bf16x4 __attribute__((ext_vector_type(4)));
typedef float f32x4 __attribute__((ext_vector_type(4)));
typedef unsigned short u16;

#define MFMA16 __builtin_amdgcn_mfma_f32_16x16x32_bf16

// ---------- helpers ----------
__device__ __forceinline__ u16 f2bf(float f) {
    unsigned u = __builtin_bit_cast(unsigned, f);
    u = u + 0x7fffu + ((u >> 16) & 1u);
    return (u16)(u >> 16);
}
__device__ __forceinline__ float bf2f(u16 s) {
    return __builtin_bit_cast(float, ((unsigned)s) << 16);
}
__device__ __forceinline__ bf16x8 pack8(float4 a, float4 b, float sc) {
    bf16x8 r;
    r[0] = (short)f2bf(a.x * sc); r[1] = (short)f2bf(a.y * sc);
    r[2] = (short)f2bf(a.z * sc); r[3] = (short)f2bf(a.w * sc);
    r[4] = (short)f2bf(b.x * sc); r[5] = (short)f2bf(b.y * sc);
    r[6] = (short)f2bf(b.z * sc); r[7] = (short)f2bf(b.w * sc);
    return r;
}
// two ds_read_b64 (row stride 136B is 8B-aligned)
__device__ __forceinline__ bf16x8 ld_q8(const u16* p) {
    bf16x4 lo = *(const bf16x4*)p;
    bf16x4 hi = *(const bf16x4*)(p + 4);
    bf16x8 r;
    r[0] = lo[0]; r[1] = lo[1]; r[2] = lo[2]; r[3] = lo[3];
    r[4] = hi[0]; r[5] = hi[1]; r[6] = hi[2]; r[7] = hi[3];
    return r;
}
__device__ __forceinline__ float rsum16(float v) {
    v += __shfl_xor(v, 1); v += __shfl_xor(v, 2);
    v += __shfl_xor(v, 4); v += __shfl_xor(v, 8);
    return v;
}

// ---------- weight f32 -> bf16 (round-4 verbatim) ----------
__global__ __launch_bounds__(256) void cvt_kernel(const float* __restrict__ src,
                                                  u16* __restrict__ dst, int n8) {
    int i = blockIdx.x * 256 + threadIdx.x;
    if (i >= n8) return;
    float4 a0 = ((const float4*)src)[i * 2];
    float4 a1 = ((const float4*)src)[i * 2 + 1];
    ((bf16x8*)dst)[i] = pack8(a0, a1, 1.0f);
}

// ---------- embedding (bf16 out, round-4 verbatim) ----------
__global__ __launch_bounds__(256) void embed_kernel(const int* __restrict__ ids,
                                                    const float4* __restrict__ item,
                                                    const float4* __restrict__ post,
                                                    u16* __restrict__ X, int M) {
    int idx = blockIdx.x * 256 + threadIdx.x;
    if (idx >= M * 16) return;
    int r = idx >> 4, c8 = idx & 15;
    int id = ids[r];
    int l = r % L;
    int p = (id != 0) ? (l + 1) : 0;
    float4 a0 = item[(size_t)id * 32 + c8 * 2];
    float4 a1 = item[(size_t)id * 32 + c8 * 2 + 1];
    float4 p0 = post[(size_t)p * 32 + c8 * 2];
    float4 p1 = post[(size_t)p * 32 + c8 * 2 + 1];
    const float sc = 11.313708498984761f;  // sqrt(128)
    float4 o0 = make_float4(a0.x * sc + p0.x, a0.y * sc + p0.y, a0.z * sc + p0.z, a0.w * sc + p0.w);
    float4 o1 = make_float4(a1.x * sc + p1.x, a1.y * sc + p1.y, a1.z * sc + p1.z, a1.w * sc + p1.w);
    *(bf16x8*)&X[(size_t)r * 128 + c8 * 8] = pack8(o0, o1, 1.0f);
}

// ---------- kernel A: per-sequence QKV + causal attention -> O16 (bf16) ----------
// THE ONE CHANGE vs round 4: replaces qkv_kernel + attn_mfma_kernel.
__global__ __launch_bounds__(512) void attnA_kernel(
        const u16* __restrict__ X16,
        const u16* __restrict__ Wq, const u16* __restrict__ Wk, const u16* __restrict__ Wv,
        const float* __restrict__ qbp, const float* __restrict__ kbp, const float* __restrict__ vbp,
        u16* __restrict__ O16) {
    __shared__ u16 lds[39744];
    u16* Ks = lds;              // [208][68]
    u16* Vt = lds + 14144;      // [64][264]
    u16* Qw = lds + 31040;      // 8 waves x [16][68]
    const int b = blockIdx.x;
    const int tid = threadIdx.x;
    const int w = tid >> 6, lane = tid & 63, g = lane >> 4, l15 = lane & 15;
    const int rp = 8 * (l15 >> 2) + (l15 & 3);
    const f32x4 czero = {0.f, 0.f, 0.f, 0.f};
    const u16* Xb = X16 + (size_t)b * L * H;
    u16* Ob = O16 + (size_t)b * L * H;
    u16* qwp = Qw + w * 1088;

    // zero Vt pad cols 208..263 (read by last PV chunk, masked by P=0)
    for (int idx = tid; idx < 64 * 56; idx += 512)
        Vt[(idx / 56) * 264 + 208 + (idx % 56)] = 0;

    // pair-balanced causal q-tiles per wave: {12},{11,0},{10,1},...,{6,5}; wave7 none
    const int ta = (w < 7) ? (12 - w) : -1;
    const int tb = (w >= 1 && w < 7) ? (w - 1) : -1;

    for (int h = 0; h < 2; ++h) {
        // ---- shared K / V^T staging (26 units over 8 waves) ----
        for (int u = w; u < 26; u += 8) {
            int rt = u >> 1;
            int xr = min(rt * 16 + l15, L - 1);
            bf16x8 xa[4];
#pragma unroll
            for (int kc = 0; kc < 4; ++kc)
                xa[kc] = *(const bf16x8*)(Xb + (size_t)xr * H + kc * 32 + g * 8);
            if (u & 1) {
                // V with swapped operands -> writes V^T directly
                f32x4 av[4];
#pragma unroll
                for (int dt = 0; dt < 4; ++dt) {
                    float4 bv4 = *(const float4*)&vbp[h * 64 + dt * 16 + g * 4];
                    av[dt] = (f32x4){bv4.x, bv4.y, bv4.z, bv4.w};
                }
#pragma unroll
                for (int kc = 0; kc < 4; ++kc)
#pragma unroll
                    for (int dt = 0; dt < 4; ++dt) {
                        bf16x8 wa = *(const bf16x8*)(Wv + (size_t)(h * 64 + dt * 16 + l15) * H + kc * 32 + g * 8);
                        av[dt] = MFMA16(wa, xa[kc], av[dt], 0, 0, 0);
                    }
#pragma unroll
                for (int dt = 0; dt < 4; ++dt)
#pragma unroll
                    for (int r = 0; r < 4; ++r)
                        Vt[(dt * 16 + g * 4 + r) * 264 + rt * 16 + l15] = f2bf(av[dt][r]);
            } else {
                f32x4 ak[4];
#pragma unroll
                for (int ct = 0; ct < 4; ++ct) {
                    float bv = kbp[h * 64 + ct * 16 + l15];
                    ak[ct] = (f32x4){bv, bv, bv, bv};
                }
#pragma unroll
                for (int kc = 0; kc < 4; ++kc)
#pragma unroll
                    for (int ct = 0; ct < 4; ++ct) {
                        bf16x8 wb = *(const bf16x8*)(Wk + (size_t)(h * 64 + ct * 16 + l15) * H + kc * 32 + g * 8);
                        ak[ct] = MFMA16(xa[kc], wb, ak[ct], 0, 0, 0);
                    }
#pragma unroll
                for (int ct = 0; ct < 4; ++ct)
#pragma unroll
                    for (int r = 0; r < 4; ++r)
                        Ks[(rt * 16 + g * 4 + r) * 68 + ct * 16 + l15] = f2bf(ak[ct][r]);
            }
        }
        __syncthreads();

        // ---- per q-tile: Q^T per-wave -> Qw patch -> attention ----
#pragma unroll
        for (int ti = 0; ti < 2; ++ti) {
            int qt = ti ? tb : ta;
            if (qt < 0) continue;
            int qrow = qt * 16 + l15;
            {
                int xr = min(qrow, L - 1);
                bf16x8 xa[4];
#pragma unroll
                for (int kc = 0; kc < 4; ++kc)
                    xa[kc] = *(const bf16x8*)(Xb + (size_t)xr * H + kc * 32 + g * 8);
                f32x4 aq[4];
#pragma unroll
                for (int dt = 0; dt < 4; ++dt) {
                    float4 bv4 = *(const float4*)&qbp[h * 64 + dt * 16 + g * 4];
                    aq[dt] = (f32x4){bv4.x, bv4.y, bv4.z, bv4.w};
                }
#pragma unroll
                for (int kc = 0; kc < 4; ++kc)
#pragma unroll
                    for (int dt = 0; dt < 4; ++dt) {
                        bf16x8 wa = *(const bf16x8*)(Wq + (size_t)(h * 64 + dt * 16 + l15) * H + kc * 32 + g * 8);
                        aq[dt] = MFMA16(wa, xa[kc], aq[dt], 0, 0, 0);
                    }
                // C-frag (d=dt*16+g*4+r, q=l15) -> Qw[q][d], scaled by 1/sqrt(hd)
#pragma unroll
                for (int dt = 0; dt < 4; ++dt)
#pragma unroll
                    for (int i2 = 0; i2 < 2; ++i2) {
                        unsigned pk = (unsigned)f2bf(aq[dt][2 * i2] * 0.125f) |
                                      ((unsigned)f2bf(aq[dt][2 * i2 + 1] * 0.125f) << 16);
                        *(unsigned*)&qwp[l15 * 68 + dt * 16 + g * 4 + 2 * i2] = pk;
                    }
                asm volatile("s_waitcnt lgkmcnt(0)" ::: "memory");
                __builtin_amdgcn_sched_barrier(0);
            }
            bf16x8 qf0 = ld_q8(&qwp[l15 * 68 + g * 8]);
            bf16x8 qf1 = ld_q8(&qwp[l15 * 68 + 32 + g * 8]);

            f32x4 o2[4];
#pragma unroll
            for (int md = 0; md < 4; ++md) o2[md] = czero;
            float mr = -1e30f, lr = 0.f;
            int kcmax = qt >> 2;
            for (int kc = 0; kc <= kcmax; ++kc) {
                int kbase = kc * 64;
                f32x4 c[4];
#pragma unroll
                for (int mt = 0; mt < 4; ++mt) {
                    int krow = min(kbase + (mt >> 1) * 32 + (mt & 1) * 4 + rp, 207);
                    bf16x8 ka0 = ld_q8(&Ks[krow * 68 + g * 8]);
                    bf16x8 ka1 = ld_q8(&Ks[krow * 68 + 32 + g * 8]);
                    c[mt] = MFMA16(ka0, qf0, czero, 0, 0, 0);
                    c[mt] = MFMA16(ka1, qf1, c[mt], 0, 0, 0);
                }
                float pm = -1e30f;
#pragma unroll
                for (int mt = 0; mt < 4; ++mt)
#pragma unroll
                    for (int r = 0; r < 4; ++r) {
                        int kact = kbase + 32 * (mt >> 1) + 4 * (mt & 1) + 8 * g + r;
                        float s = (kact <= qrow) ? c[mt][r] : -1e30f;
                        c[mt][r] = s;
                        pm = fmaxf(pm, s);
                    }
                pm = fmaxf(pm, __shfl_xor(pm, 16));
                pm = fmaxf(pm, __shfl_xor(pm, 32));
                float mnew = fmaxf(mr, pm);
                float sf = __expf(mr - mnew);
                mr = mnew;
                float ps = 0.f;
#pragma unroll
                for (int mt = 0; mt < 4; ++mt)
#pragma unroll
                    for (int r = 0; r < 4; ++r) {
                        float p = __expf(c[mt][r] - mnew);
                        c[mt][r] = p;
                        ps += p;
                    }
                ps += __shfl_xor(ps, 16);
                ps += __shfl_xor(ps, 32);
                lr = lr * sf + ps;
#pragma unroll
                for (int md = 0; md < 4; ++md)
#pragma unroll
                    for (int r = 0; r < 4; ++r) o2[md][r] *= sf;
#pragma unroll
                for (int ks = 0; ks < 2; ++ks) {
                    bf16x8 pb;
#pragma unroll
                    for (int j = 0; j < 8; ++j)
                        pb[j] = (short)f2bf(c[2 * ks + (j >> 2)][j & 3]);
#pragma unroll
                    for (int md = 0; md < 4; ++md) {
                        bf16x8 va = *(const bf16x8*)&Vt[(md * 16 + l15) * 264 + kbase + ks * 32 + g * 8];
                        o2[md] = MFMA16(va, pb, o2[md], 0, 0, 0);
                    }
                }
            }
            if (qrow < L) {
                float inv = 1.0f / lr;
#pragma unroll
                for (int md = 0; md < 4; ++md) {
                    unsigned p0 = (unsigned)f2bf(o2[md][0] * inv) | ((unsigned)f2bf(o2[md][1] * inv) << 16);
                    unsigned p1 = (unsigned)f2bf(o2[md][2] * inv) | ((unsigned)f2bf(o2[md][3] * inv) << 16);
                    uint2 uu; uu.x = p0; uu.y = p1;
                    *(uint2*)(Ob + (size_t)qrow * H + h * 64 + md * 16 + g * 4) = uu;
                }
            }
        }
        __syncthreads();
    }
}

// ---------- fused O-proj + residual + LN1 + FFN1 (round-4 verbatim) ----------
__global__ __launch_bounds__(256) void oproj_ffn1_kernel(const u16* __restrict__ A,
        const u16* __restrict__ Wo, const float* __restrict__ ob,
        const u16* __restrict__ Xres, const float* __restrict__ gma, const float* __restrict__ bta,
        const u16* __restrict__ W1, const float* __restrict__ b1f,
        u16* __restrict__ Xout, u16* __restrict__ F1, int M) {
    __shared__ u16 Xs[128 * XSS];
    __shared__ u16 Ot[4][16 * XSS];
    int tid = threadIdx.x, w = tid >> 6, lane = tid & 63, g = lane >> 4, l15 = lane & 15;
    int row0 = blockIdx.x * 128;
    int rw = row0 + w * 32;
    size_t ar0 = (size_t)min(rw + l15, M - 1) * 128;
    size_t ar1 = (size_t)min(rw + 16 + l15, M - 1) * 128;
    int ko = g * 8;

    f32x4 acc[2][8];
#pragma unroll
    for (int nt = 0; nt < 8; ++nt) {
        float bv = ob[nt * 16 + l15];
        acc[0][nt] = (f32x4){bv, bv, bv, bv};
        acc[1][nt] = (f32x4){bv, bv, bv, bv};
    }
#pragma unroll
    for (int kc = 0; kc < 4; ++kc) {
        bf16x8 a0 = *(const bf16x8*)(A + ar0 + kc * 32 + ko);
        bf16x8 a1 = *(const bf16x8*)(A + ar1 + kc * 32 + ko);
#pragma unroll
        for (int nt = 0; nt < 8; ++nt) {
            bf16x8 b = *(const bf16x8*)(Wo + ((size_t)(nt * 16 + l15) << 7) + kc * 32 + ko);
            acc[0][nt] = MFMA16(a0, b, acc[0][nt], 0, 0, 0);
            acc[1][nt] = MFMA16(a1, b, acc[1][nt], 0, 0, 0);
        }
    }
    float gg[8], bb[8];
#pragma unroll
    for (int nt = 0; nt < 8; ++nt) { gg[nt] = gma[nt * 16 + l15]; bb[nt] = bta[nt * 16 + l15]; }
#pragma unroll
    for (int mt = 0; mt < 2; ++mt) {
#pragma unroll
        for (int r = 0; r < 4; ++r) {
            int rowl = w * 32 + mt * 16 + g * 4 + r;
            size_t rb = (size_t)min(row0 + rowl, M - 1) * 128;
            float v[8];
            float s = 0.f;
#pragma unroll
            for (int nt = 0; nt < 8; ++nt) { v[nt] = acc[mt][nt][r] + bf2f(Xres[rb + nt * 16 + l15]); s += v[nt]; }
            s += __shfl_xor(s, 1); s += __shfl_xor(s, 2); s += __shfl_xor(s, 4); s += __shfl_xor(s, 8);
            float mean = s * 0.0078125f;
            float s2 = 0.f;
#pragma unroll
            for (int nt = 0; nt < 8; ++nt) { float d = v[nt] - mean; s2 += d * d; }
            s2 += __shfl_xor(s2, 1); s2 += __shfl_xor(s2, 2); s2 += __shfl_xor(s2, 4); s2 += __shfl_xor(s2, 8);
            float inv = rsqrtf(s2 * 0.0078125f + 1e-8f);
#pragma unroll
            for (int nt = 0; nt < 8; ++nt)
                Xs[rowl * XSS + nt * 16 + l15] = f2bf((v[nt] - mean) * inv * gg[nt] + bb[nt]);
        }
    }
    __syncthreads();

#pragma unroll
    for (int it = 0; it < 8; ++it) {
        int idx = it * 256 + tid;
        int r = idx >> 4, c8 = idx & 15;
        int grow = row0 + r;
        if (grow < M)
            *(bf16x8*)(Xout + (size_t)grow * 128 + c8 * 8) = *(const bf16x8*)&Xs[r * XSS + c8 * 8];
    }

    int arow = w * 32 + l15;
    f32x4 acc2[2][8];
#pragma unroll
    for (int nt = 0; nt < 8; ++nt) {
        float bv = b1f[nt * 16 + l15];
        acc2[0][nt] = (f32x4){bv, bv, bv, bv};
        acc2[1][nt] = (f32x4){bv, bv, bv, bv};
    }
#pragma unroll
    for (int kc = 0; kc < 4; ++kc) {
        bf16x8 a0 = *(const bf16x8*)&Xs[arow * XSS + kc * 32 + ko];
        bf16x8 a1 = *(const bf16x8*)&Xs[(arow + 16) * XSS + kc * 32 + ko];
#pragma unroll
        for (int nt = 0; nt < 8; ++nt) {
            bf16x8 b = *(const bf16x8*)(W1 + ((size_t)(nt * 16 + l15) << 7) + kc * 32 + ko);
            acc2[0][nt] = MFMA16(a0, b, acc2[0][nt], 0, 0, 0);
            acc2[1][nt] = MFMA16(a1, b, acc2[1][nt], 0, 0, 0);
        }
    }
#pragma unroll
    for (int mt = 0; mt < 2; ++mt) {
#pragma unroll
        for (int r = 0; r < 4; ++r) {
            int ml = g * 4 + r;
#pragma unroll
            for (int nt = 0; nt < 8; ++nt)
                Ot[w][ml * XSS + nt * 16 + l15] = f2bf(fmaxf(acc2[mt][nt][r], 0.f));
        }
        asm volatile("s_waitcnt lgkmcnt(0)" ::: "memory");
#pragma unroll
        for (int j = 0; j < 4; ++j) {
            int chunk = j * 64 + lane;
            int rr = chunk >> 4, c16 = chunk & 15;
            bf16x8 v = *(const bf16x8*)&Ot[w][rr * XSS + c16 * 8];
            int grow = row0 + w * 32 + mt * 16 + rr;
            if (grow < M) *(bf16x8*)(F1 + (size_t)grow * 128 + c16 * 8) = v;
        }
        asm volatile("s_waitcnt lgkmcnt(0)" ::: "memory");
    }
}

// ---------- FFN2 + residual + LN2 (+ final LN + logits when fin) (round-4 verbatim) ----------
__global__ __launch_bounds__(256) void ffn2_ln_kernel(const u16* __restrict__ A,
        const u16* __restrict__ W2, const float* __restrict__ bias,
        const u16* __restrict__ Xres, const float* __restrict__ gma, const float* __restrict__ bta,
        const float* __restrict__ gf, const float* __restrict__ bff, int fin,
        u16* __restrict__ Xout, const float* __restrict__ item,
        const int* __restrict__ pid, const int* __restrict__ nid,
        float* __restrict__ out, int gofs, int M) {
    __shared__ u16 Ot[4][16 * XSS];
    int tid = threadIdx.x, w = tid >> 6, lane = tid & 63, g = lane >> 4, l15 = lane & 15;
    int row0 = blockIdx.x * 128;
    int rw = row0 + w * 32;
    size_t ar0 = (size_t)min(rw + l15, M - 1) * 128;
    size_t ar1 = (size_t)min(rw + 16 + l15, M - 1) * 128;
    int ko = g * 8;

    f32x4 acc[2][8];
#pragma unroll
    for (int nt = 0; nt < 8; ++nt) {
        float bv = bias[nt * 16 + l15];
        acc[0][nt] = (f32x4){bv, bv, bv, bv};
        acc[1][nt] = (f32x4){bv, bv, bv, bv};
    }
#pragma unroll
    for (int kc = 0; kc < 4; ++kc) {
        bf16x8 a0 = *(const bf16x8*)(A + ar0 + kc * 32 + ko);
        bf16x8 a1 = *(const bf16x8*)(A + ar1 + kc * 32 + ko);
#pragma unroll
        for (int nt = 0; nt < 8; ++nt) {
            bf16x8 b = *(const bf16x8*)(W2 + ((size_t)(nt * 16 + l15) << 7) + kc * 32 + ko);
            acc[0][nt] = MFMA16(a0, b, acc[0][nt], 0, 0, 0);
            acc[1][nt] = MFMA16(a1, b, acc[1][nt], 0, 0, 0);
        }
    }
    float gg[8], bb[8], gg2[8], bb2[8];
#pragma unroll
    for (int nt = 0; nt < 8; ++nt) {
        gg[nt] = gma[nt * 16 + l15]; bb[nt] = bta[nt * 16 + l15];
        gg2[nt] = gf[nt * 16 + l15]; bb2[nt] = bff[nt * 16 + l15];
    }
#pragma unroll
    for (int mt = 0; mt < 2; ++mt) {
#pragma unroll
        for (int r = 0; r < 4; ++r) {
            int row = row0 + w * 32 + mt * 16 + g * 4 + r;
            size_t rb = (size_t)min(row, M - 1) * 128;
            float v[8];
            float s = 0.f;
#pragma unroll
            for (int nt = 0; nt < 8; ++nt) { v[nt] = acc[mt][nt][r] + bf2f(Xres[rb + nt * 16 + l15]); s += v[nt]; }
            s += __shfl_xor(s, 1); s += __shfl_xor(s, 2); s += __shfl_xor(s, 4); s += __shfl_xor(s, 8);
            float mean = s * 0.0078125f;
            float s2 = 0.f;
#pragma unroll
            for (int nt = 0; nt < 8; ++nt) { float d = v[nt] - mean; s2 += d * d; }
            s2 += __shfl_xor(s2, 1); s2 += __shfl_xor(s2, 2); s2 += __shfl_xor(s2, 4); s2 += __shfl_xor(s2, 8);
            float inv = rsqrtf(s2 * 0.0078125f + 1e-8f);
#pragma unroll
            for (int nt = 0; nt < 8; ++nt) v[nt] = (v[nt] - mean) * inv * gg[nt] + bb[nt];
            if (fin) {
                float t = 0.f;
#pragma unroll
                for (int nt = 0; nt < 8; ++nt) t += v[nt];
                t += __shfl_xor(t, 1); t += __shfl_xor(t, 2); t += __shfl_xor(t, 4); t += __shfl_xor(t, 8);
                float mean2 = t * 0.0078125f;
                float t2 = 0.f;
#pragma unroll
                for (int nt = 0; nt < 8; ++nt) { float d = v[nt] - mean2; t2 += d * d; }
                t2 += __shfl_xor(t2, 1); t2 += __shfl_xor(t2, 2); t2 += __shfl_xor(t2, 4); t2 += __shfl_xor(t2, 8);
                float inv2 = rsqrtf(t2 * 0.0078125f + 1e-8f);
#pragma unroll
                for (int nt = 0; nt < 8; ++nt) v[nt] = (v[nt] - mean2) * inv2 * gg2[nt] + bb2[nt];
                int gr = gofs + row;
                const float* prow = item + (size_t)pid[gr] * 128;
                const float* nrow = item + (size_t)nid[gr] * 128;
                float sp = 0.f, sn = 0.f;
#pragma unroll
                for (int nt = 0; nt < 8; ++nt) {
                    sp += v[nt] * prow[nt * 16 + l15];
                    sn += v[nt] * nrow[nt * 16 + l15];
                }
                sp += __shfl_xor(sp, 1); sp += __shfl_xor(sp, 2); sp += __shfl_xor(sp, 4); sp += __shfl_xor(sp, 8);
                sn += __shfl_xor(sn, 1); sn += __shfl_xor(sn, 2); sn += __shfl_xor(sn, 4); sn += __shfl_xor(sn, 8);
                if (l15 == 0 && row < M) {
                    out[gr] = sp;
                    out[(size_t)BTOT * L + gr] = sn;
                }
            } else {
                int ml = g * 4 + r;
#pragma unroll
                for (int nt = 0; nt < 8; ++nt)
                    Ot[w][ml * XSS + nt * 16 + l15] = f2bf(v[nt]);
            }
        }
        if (!fin) {
            asm volatile("s_waitcnt lgkmcnt(0)" ::: "memory");
#pragma unroll
            for (int j = 0; j < 4; ++j) {
                int chunk = j * 64 + lane;
                int rr = chunk >> 4, c16 = chunk & 15;
                bf16x8 v = *(const bf16x8*)&Ot[w][rr * XSS + c16 * 8];
                int grow = row0 + w * 32 + mt * 16 + rr;
                if (grow < M) *(bf16x8*)(Xout + (size_t)grow * 128 + c16 * 8) = v;
            }
            asm volatile("s_waitcnt lgkmcnt(0)" ::: "memory");
        }
    }
}

extern "C" void kernel_launch(void* const* d_in, const int* in_sizes, int n_in,
                              void* d_out, int out_size, void* d_ws, size_t ws_size,
                              hipStream_t stream) {
    const int* log_seqs = (const int*)d_in[1];
    const int* pos_seqs = (const int*)d_in[2];
    const int* neg_seqs = (const int*)d_in[3];
    const float* item = (const float*)d_in[4];
    const float* post = (const float*)d_in[5];
    const float* qw = (const float*)d_in[6];
    const float* kw = (const float*)d_in[7];
    const float* vw = (const float*)d_in[8];
    const float* ow = (const float*)d_in[9];
    const float* qb = (const float*)d_in[10];
    const float* kb = (const float*)d_in[11];
    const float* vb = (const float*)d_in[12];
    const float* ob = (const float*)d_in[13];
    const float* w1 = (const float*)d_in[14];
    const float* b1 = (const float*)d_in[15];
    const float* w2 = (const float*)d_in[16];
    const float* b2 = (const float*)d_in[17];
    const float* ln1g = (const float*)d_in[18];
    const float* ln1b = (const float*)d_in[19];
    const float* ln2g = (const float*)d_in[20];
    const float* ln2b = (const float*)d_in[21];
    const float* lnfg = (const float*)d_in[22];
    const float* lnfb = (const float*)d_in[23];
    float* out = (float*)d_out;

    // round-4 layout: X,Q,K,V bf16 + weights (K16 holds F1; V16 unused by attnA)
    int cb = 512;
    while (cb > 8 && (size_t)cb * L * H * 8 + 12 * HH * 2 > ws_size) cb >>= 1;
    size_t nbe = (size_t)cb * L * H;
    u16* X16 = (u16*)d_ws;
    u16* Q16 = X16 + nbe;
    u16* K16 = Q16 + nbe;
    u16* V16 = K16 + nbe;
    u16* w16 = V16 + nbe;
    (void)V16;

    const float* wsrc[6] = {qw, kw, vw, ow, w1, w2};
    int n8 = NB * HH / 8;
    for (int t = 0; t < 6; ++t)
        cvt_kernel<<<(n8 + 255) / 256, 256, 0, stream>>>(wsrc[t], w16 + (size_t)t * NB * HH, n8);

    for (int b0 = 0; b0 < BTOT; b0 += cb) {
        int M = cb * L;
        int gblk = (M + 127) / 128;
        embed_kernel<<<(M * 16 + 255) / 256, 256, 0, stream>>>(log_seqs + (size_t)b0 * L,
                                                               (const float4*)item, (const float4*)post,
                                                               X16, M);
        for (int i = 0; i < NB; ++i) {
            size_t wo = (size_t)i * HH;
            int bofs = i * H;
            attnA_kernel<<<cb, 512, 0, stream>>>(X16,
                    w16 + 0 * NB * HH + wo, w16 + 1 * NB * HH + wo, w16 + 2 * NB * HH + wo,
                    qb + bofs, kb + bofs, vb + bofs, Q16);
            oproj_ffn1_kernel<<<gblk, 256, 0, stream>>>(Q16, w16 + 3 * NB * HH + wo, ob + bofs,
                    X16, ln1g + bofs, ln1b + bofs,
                    w16 + 4 * NB * HH + wo, b1 + bofs, X16, K16, M);
            ffn2_ln_kernel<<<gblk, 256, 0, stream>>>(K16, w16 + 5 * NB * HH + wo, b2 + bofs,
                    X16, ln2g + bofs, ln2b + bofs, lnfg, lnfb, (i == NB - 1) ? 1 : 0,
                    X16, item, pos_seqs, neg_seqs, out, b0 * L, M);
        }
    }
}

// Round 9
// 1700.689 us; speedup vs baseline: 1.3545x; 1.0355x over previous
//
#include <hip/hip_runtime.h>
#include <math.h>

#define L 200
#define H 128
#define HD 64
#define NB 2
#define BTOT 2048
#define HH (H * H)
#define XSS 136   // LDS row stride in shorts (272B, 16B-aligned)

typedef short bf16x8 __attribute__((ext_vector_type(8)));
typedef short bf16x4 __attribute__((ext_vector_type(4)));
typedef float f32x4 __attribute__((ext_vector_type(4)));
typedef unsigned short u16;

#define MFMA16 __builtin_amdgcn_mfma_f32_16x16x32_bf16

// ---------- helpers ----------
__device__ __forceinline__ u16 f2bf(float f) {
    unsigned u = __builtin_bit_cast(unsigned, f);
    u = u + 0x7fffu + ((u >> 16) & 1u);
    return (u16)(u >> 16);
}
__device__ __forceinline__ float bf2f(u16 s) {
    return __builtin_bit_cast(float, ((unsigned)s) << 16);
}
__device__ __forceinline__ bf16x8 pack8(float4 a, float4 b, float sc) {
    bf16x8 r;
    r[0] = (short)f2bf(a.x * sc); r[1] = (short)f2bf(a.y * sc);
    r[2] = (short)f2bf(a.z * sc); r[3] = (short)f2bf(a.w * sc);
    r[4] = (short)f2bf(b.x * sc); r[5] = (short)f2bf(b.y * sc);
    r[6] = (short)f2bf(b.z * sc); r[7] = (short)f2bf(b.w * sc);
    return r;
}
// two ds_read_b64 (row stride 136B is 8B-aligned)
__device__ __forceinline__ bf16x8 ld_q8(const u16* p) {
    bf16x4 lo = *(const bf16x4*)p;
    bf16x4 hi = *(const bf16x4*)(p + 4);
    bf16x8 r;
    r[0] = lo[0]; r[1] = lo[1]; r[2] = lo[2]; r[3] = lo[3];
    r[4] = hi[0]; r[5] = hi[1]; r[6] = hi[2]; r[7] = hi[3];
    return r;
}

// ---------- weight f32 -> bf16 ----------
__global__ __launch_bounds__(256) void cvt_kernel(const float* __restrict__ src,
                                                  u16* __restrict__ dst, int n8) {
    int i = blockIdx.x * 256 + threadIdx.x;
    if (i >= n8) return;
    float4 a0 = ((const float4*)src)[i * 2];
    float4 a1 = ((const float4*)src)[i * 2 + 1];
    ((bf16x8*)dst)[i] = pack8(a0, a1, 1.0f);
}

// ---------- embedding (bf16 out) ----------
__global__ __launch_bounds__(256) void embed_kernel(const int* __restrict__ ids,
                                                    const float4* __restrict__ item,
                                                    const float4* __restrict__ post,
                                                    u16* __restrict__ X, int M) {
    int idx = blockIdx.x * 256 + threadIdx.x;
    if (idx >= M * 16) return;
    int r = idx >> 4, c8 = idx & 15;
    int id = ids[r];
    int l = r % L;
    int p = (id != 0) ? (l + 1) : 0;
    float4 a0 = item[(size_t)id * 32 + c8 * 2];
    float4 a1 = item[(size_t)id * 32 + c8 * 2 + 1];
    float4 p0 = post[(size_t)p * 32 + c8 * 2];
    float4 p1 = post[(size_t)p * 32 + c8 * 2 + 1];
    const float sc = 11.313708498984761f;  // sqrt(128)
    float4 o0 = make_float4(a0.x * sc + p0.x, a0.y * sc + p0.y, a0.z * sc + p0.z, a0.w * sc + p0.w);
    float4 o1 = make_float4(a1.x * sc + p1.x, a1.y * sc + p1.y, a1.z * sc + p1.z, a1.w * sc + p1.w);
    *(bf16x8*)&X[(size_t)r * 128 + c8 * 8] = pack8(o0, o1, 1.0f);
}

// ---------- fused QKV: swapped-operand MFMA, direct uint2 stores, no epilogue LDS ----------
__global__ __launch_bounds__(256) void qkv_kernel(const u16* __restrict__ X,
        const u16* __restrict__ wq, const u16* __restrict__ wk, const u16* __restrict__ wv,
        const float* __restrict__ qb, const float* __restrict__ kb, const float* __restrict__ vb,
        u16* __restrict__ Qo, u16* __restrict__ Ko, u16* __restrict__ Vo, int M) {
    __shared__ u16 Xs[128 * XSS];
    int tid = threadIdx.x, w = tid >> 6, lane = tid & 63, g = lane >> 4, l15 = lane & 15;
    int row0 = blockIdx.x * 128;
#pragma unroll
    for (int it = 0; it < 8; ++it) {
        int idx = it * 256 + tid;
        int r = idx >> 4, c8 = idx & 15;
        size_t gr = (size_t)min(row0 + r, M - 1);
        *(bf16x8*)&Xs[r * XSS + c8 * 8] = *(const bf16x8*)(X + gr * 128 + c8 * 8);
    }
    __syncthreads();

    // B-fragments: this wave's two row-tiles (rows in lane l15)
    int r0 = w * 16 + l15, r1 = (w + 4) * 16 + l15;
    bf16x8 xb0[4], xb1[4];
#pragma unroll
    for (int kc = 0; kc < 4; ++kc) {
        xb0[kc] = *(const bf16x8*)&Xs[r0 * XSS + kc * 32 + g * 8];
        xb1[kc] = *(const bf16x8*)&Xs[r1 * XSS + kc * 32 + g * 8];
    }

#pragma unroll
    for (int p = 0; p < 3; ++p) {
        const u16* Wp = p == 0 ? wq : (p == 1 ? wk : wv);
        const float* bp = p == 0 ? qb : (p == 1 ? kb : vb);
        u16* Op = p == 0 ? Qo : (p == 1 ? Ko : Vo);
        const float scale = p == 0 ? 0.125f : 1.0f;

        f32x4 acc[2][8];
#pragma unroll
        for (int dt = 0; dt < 8; ++dt) {
            float4 bv4 = *(const float4*)&bp[dt * 16 + g * 4];
            acc[0][dt] = (f32x4){bv4.x, bv4.y, bv4.z, bv4.w};
            acc[1][dt] = acc[0][dt];
        }
#pragma unroll
        for (int kc = 0; kc < 4; ++kc) {
#pragma unroll
            for (int dt = 0; dt < 8; ++dt) {
                bf16x8 wa = *(const bf16x8*)(Wp + ((size_t)(dt * 16 + l15) << 7) + kc * 32 + g * 8);
                acc[0][dt] = MFMA16(wa, xb0[kc], acc[0][dt], 0, 0, 0);
                acc[1][dt] = MFMA16(wa, xb1[kc], acc[1][dt], 0, 0, 0);
            }
        }
#pragma unroll
        for (int t2 = 0; t2 < 2; ++t2) {
            int grow = row0 + (t2 ? r1 : r0);
            if (grow < M) {
                u16* dst = Op + (size_t)grow * 128 + g * 4;
#pragma unroll
                for (int dt = 0; dt < 8; ++dt) {
                    f32x4 a4 = t2 ? acc[1][dt] : acc[0][dt];
                    unsigned p0 = (unsigned)f2bf(a4[0] * scale) | ((unsigned)f2bf(a4[1] * scale) << 16);
                    unsigned p1 = (unsigned)f2bf(a4[2] * scale) | ((unsigned)f2bf(a4[3] * scale) << 16);
                    uint2 uu; uu.x = p0; uu.y = p1;
                    *(uint2*)(dst + dt * 16) = uu;
                }
            }
        }
    }
}

// ---------- fused O-proj + residual + LN1 + FFN1 (FFN1 swapped, direct F1 stores) ----------
__global__ __launch_bounds__(256) void oproj_ffn1_kernel(const u16* __restrict__ A,
        const u16* __restrict__ Wo, const float* __restrict__ ob,
        const u16* __restrict__ Xres, const float* __restrict__ gma, const float* __restrict__ bta,
        const u16* __restrict__ W1, const float* __restrict__ b1f,
        u16* __restrict__ Xout, u16* __restrict__ F1, int M) {
    __shared__ u16 Xs[128 * XSS];
    int tid = threadIdx.x, w = tid >> 6, lane = tid & 63, g = lane >> 4, l15 = lane & 15;
    int row0 = blockIdx.x * 128;
    int rw = row0 + w * 32;
    size_t ar0 = (size_t)min(rw + l15, M - 1) * 128;
    size_t ar1 = (size_t)min(rw + 16 + l15, M - 1) * 128;
    int ko = g * 8;

    // ---- O-proj GEMM (non-swapped: LN needs cols in lanes) ----
    f32x4 acc[2][8];
#pragma unroll
    for (int nt = 0; nt < 8; ++nt) {
        float bv = ob[nt * 16 + l15];
        acc[0][nt] = (f32x4){bv, bv, bv, bv};
        acc[1][nt] = (f32x4){bv, bv, bv, bv};
    }
#pragma unroll
    for (int kc = 0; kc < 4; ++kc) {
        bf16x8 a0 = *(const bf16x8*)(A + ar0 + kc * 32 + ko);
        bf16x8 a1 = *(const bf16x8*)(A + ar1 + kc * 32 + ko);
#pragma unroll
        for (int nt = 0; nt < 8; ++nt) {
            bf16x8 b = *(const bf16x8*)(Wo + ((size_t)(nt * 16 + l15) << 7) + kc * 32 + ko);
            acc[0][nt] = MFMA16(a0, b, acc[0][nt], 0, 0, 0);
            acc[1][nt] = MFMA16(a1, b, acc[1][nt], 0, 0, 0);
        }
    }
    // ---- residual + LN1 -> Xs ----
    float gg[8], bb[8];
#pragma unroll
    for (int nt = 0; nt < 8; ++nt) { gg[nt] = gma[nt * 16 + l15]; bb[nt] = bta[nt * 16 + l15]; }
#pragma unroll
    for (int mt = 0; mt < 2; ++mt) {
#pragma unroll
        for (int r = 0; r < 4; ++r) {
            int rowl = w * 32 + mt * 16 + g * 4 + r;
            size_t rb = (size_t)min(row0 + rowl, M - 1) * 128;
            float v[8];
            float s = 0.f;
#pragma unroll
            for (int nt = 0; nt < 8; ++nt) { v[nt] = acc[mt][nt][r] + bf2f(Xres[rb + nt * 16 + l15]); s += v[nt]; }
            s += __shfl_xor(s, 1); s += __shfl_xor(s, 2); s += __shfl_xor(s, 4); s += __shfl_xor(s, 8);
            float mean = s * 0.0078125f;
            float s2 = 0.f;
#pragma unroll
            for (int nt = 0; nt < 8; ++nt) { float d = v[nt] - mean; s2 += d * d; }
            s2 += __shfl_xor(s2, 1); s2 += __shfl_xor(s2, 2); s2 += __shfl_xor(s2, 4); s2 += __shfl_xor(s2, 8);
            float inv = rsqrtf(s2 * 0.0078125f + 1e-8f);
#pragma unroll
            for (int nt = 0; nt < 8; ++nt)
                Xs[rowl * XSS + nt * 16 + l15] = f2bf((v[nt] - mean) * inv * gg[nt] + bb[nt]);
        }
    }
    __syncthreads();

    // ---- copy Xs -> Xout (vectorized) ----
#pragma unroll
    for (int it = 0; it < 8; ++it) {
        int idx = it * 256 + tid;
        int r = idx >> 4, c8 = idx & 15;
        int grow = row0 + r;
        if (grow < M)
            *(bf16x8*)(Xout + (size_t)grow * 128 + c8 * 8) = *(const bf16x8*)&Xs[r * XSS + c8 * 8];
    }

    // ---- FFN1 swapped-operand: output cols in regs -> direct uint2 stores ----
    int fr0 = w * 16 + l15, fr1 = (w + 4) * 16 + l15;
    bf16x8 x0[4], x1[4];
#pragma unroll
    for (int kc = 0; kc < 4; ++kc) {
        x0[kc] = *(const bf16x8*)&Xs[fr0 * XSS + kc * 32 + g * 8];
        x1[kc] = *(const bf16x8*)&Xs[fr1 * XSS + kc * 32 + g * 8];
    }
    f32x4 acc2[2][8];
#pragma unroll
    for (int dt = 0; dt < 8; ++dt) {
        float4 bv4 = *(const float4*)&b1f[dt * 16 + g * 4];
        acc2[0][dt] = (f32x4){bv4.x, bv4.y, bv4.z, bv4.w};
        acc2[1][dt] = acc2[0][dt];
    }
#pragma unroll
    for (int kc = 0; kc < 4; ++kc) {
#pragma unroll
        for (int dt = 0; dt < 8; ++dt) {
            bf16x8 wa = *(const bf16x8*)(W1 + ((size_t)(dt * 16 + l15) << 7) + kc * 32 + g * 8);
            acc2[0][dt] = MFMA16(wa, x0[kc], acc2[0][dt], 0, 0, 0);
            acc2[1][dt] = MFMA16(wa, x1[kc], acc2[1][dt], 0, 0, 0);
        }
    }
#pragma unroll
    for (int t2 = 0; t2 < 2; ++t2) {
        int grow = row0 + (t2 ? fr1 : fr0);
        if (grow < M) {
            u16* dst = F1 + (size_t)grow * 128 + g * 4;
#pragma unroll
            for (int dt = 0; dt < 8; ++dt) {
                f32x4 a4 = t2 ? acc2[1][dt] : acc2[0][dt];
                unsigned p0 = (unsigned)f2bf(fmaxf(a4[0], 0.f)) | ((unsigned)f2bf(fmaxf(a4[1], 0.f)) << 16);
                unsigned p1 = (unsigned)f2bf(fmaxf(a4[2], 0.f)) | ((unsigned)f2bf(fmaxf(a4[3], 0.f)) << 16);
                uint2 uu; uu.x = p0; uu.y = p1;
                *(uint2*)(dst + dt * 16) = uu;
            }
        }
    }
}

// ---------- FFN2 + residual + LN2 (+ final LN + logits when fin) (round-4 verbatim) ----------
__global__ __launch_bounds__(256) void ffn2_ln_kernel(const u16* __restrict__ A,
        const u16* __restrict__ W2, const float* __restrict__ bias,
        const u16* __restrict__ Xres, const float* __restrict__ gma, const float* __restrict__ bta,
        const float* __restrict__ gf, const float* __restrict__ bff, int fin,
        u16* __restrict__ Xout, const float* __restrict__ item,
        const int* __restrict__ pid, const int* __restrict__ nid,
        float* __restrict__ out, int gofs, int M) {
    __shared__ u16 Ot[4][16 * XSS];
    int tid = threadIdx.x, w = tid >> 6, lane = tid & 63, g = lane >> 4, l15 = lane & 15;
    int row0 = blockIdx.x * 128;
    int rw = row0 + w * 32;
    size_t ar0 = (size_t)min(rw + l15, M - 1) * 128;
    size_t ar1 = (size_t)min(rw + 16 + l15, M - 1) * 128;
    int ko = g * 8;

    f32x4 acc[2][8];
#pragma unroll
    for (int nt = 0; nt < 8; ++nt) {
        float bv = bias[nt * 16 + l15];
        acc[0][nt] = (f32x4){bv, bv, bv, bv};
        acc[1][nt] = (f32x4){bv, bv, bv, bv};
    }
#pragma unroll
    for (int kc = 0; kc < 4; ++kc) {
        bf16x8 a0 = *(const bf16x8*)(A + ar0 + kc * 32 + ko);
        bf16x8 a1 = *(const bf16x8*)(A + ar1 + kc * 32 + ko);
#pragma unroll
        for (int nt = 0; nt < 8; ++nt) {
            bf16x8 b = *(const bf16x8*)(W2 + ((size_t)(nt * 16 + l15) << 7) + kc * 32 + ko);
            acc[0][nt] = MFMA16(a0, b, acc[0][nt], 0, 0, 0);
            acc[1][nt] = MFMA16(a1, b, acc[1][nt], 0, 0, 0);
        }
    }
    float gg[8], bb[8], gg2[8], bb2[8];
#pragma unroll
    for (int nt = 0; nt < 8; ++nt) {
        gg[nt] = gma[nt * 16 + l15]; bb[nt] = bta[nt * 16 + l15];
        gg2[nt] = gf[nt * 16 + l15]; bb2[nt] = bff[nt * 16 + l15];
    }
#pragma unroll
    for (int mt = 0; mt < 2; ++mt) {
#pragma unroll
        for (int r = 0; r < 4; ++r) {
            int row = row0 + w * 32 + mt * 16 + g * 4 + r;
            size_t rb = (size_t)min(row, M - 1) * 128;
            float v[8];
            float s = 0.f;
#pragma unroll
            for (int nt = 0; nt < 8; ++nt) { v[nt] = acc[mt][nt][r] + bf2f(Xres[rb + nt * 16 + l15]); s += v[nt]; }
            s += __shfl_xor(s, 1); s += __shfl_xor(s, 2); s += __shfl_xor(s, 4); s += __shfl_xor(s, 8);
            float mean = s * 0.0078125f;
            float s2 = 0.f;
#pragma unroll
            for (int nt = 0; nt < 8; ++nt) { float d = v[nt] - mean; s2 += d * d; }
            s2 += __shfl_xor(s2, 1); s2 += __shfl_xor(s2, 2); s2 += __shfl_xor(s2, 4); s2 += __shfl_xor(s2, 8);
            float inv = rsqrtf(s2 * 0.0078125f + 1e-8f);
#pragma unroll
            for (int nt = 0; nt < 8; ++nt) v[nt] = (v[nt] - mean) * inv * gg[nt] + bb[nt];
            if (fin) {
                float t = 0.f;
#pragma unroll
                for (int nt = 0; nt < 8; ++nt) t += v[nt];
                t += __shfl_xor(t, 1); t += __shfl_xor(t, 2); t += __shfl_xor(t, 4); t += __shfl_xor(t, 8);
                float mean2 = t * 0.0078125f;
                float t2 = 0.f;
#pragma unroll
                for (int nt = 0; nt < 8; ++nt) { float d = v[nt] - mean2; t2 += d * d; }
                t2 += __shfl_xor(t2, 1); t2 += __shfl_xor(t2, 2); t2 += __shfl_xor(t2, 4); t2 += __shfl_xor(t2, 8);
                float inv2 = rsqrtf(t2 * 0.0078125f + 1e-8f);
#pragma unroll
                for (int nt = 0; nt < 8; ++nt) v[nt] = (v[nt] - mean2) * inv2 * gg2[nt] + bb2[nt];
                int gr = gofs + row;
                const float* prow = item + (size_t)pid[gr] * 128;
                const float* nrow = item + (size_t)nid[gr] * 128;
                float sp = 0.f, sn = 0.f;
#pragma unroll
                for (int nt = 0; nt < 8; ++nt) {
                    sp += v[nt] * prow[nt * 16 + l15];
                    sn += v[nt] * nrow[nt * 16 + l15];
                }
                sp += __shfl_xor(sp, 1); sp += __shfl_xor(sp, 2); sp += __shfl_xor(sp, 4); sp += __shfl_xor(sp, 8);
                sn += __shfl_xor(sn, 1); sn += __shfl_xor(sn, 2); sn += __shfl_xor(sn, 4); sn += __shfl_xor(sn, 8);
                if (l15 == 0 && row < M) {
                    out[gr] = sp;
                    out[(size_t)BTOT * L + gr] = sn;
                }
            } else {
                int ml = g * 4 + r;
#pragma unroll
                for (int nt = 0; nt < 8; ++nt)
                    Ot[w][ml * XSS + nt * 16 + l15] = f2bf(v[nt]);
            }
        }
        if (!fin) {
            asm volatile("s_waitcnt lgkmcnt(0)" ::: "memory");
#pragma unroll
            for (int j = 0; j < 4; ++j) {
                int chunk = j * 64 + lane;
                int rr = chunk >> 4, c16 = chunk & 15;
                bf16x8 v = *(const bf16x8*)&Ot[w][rr * XSS + c16 * 8];
                int grow = row0 + w * 32 + mt * 16 + rr;
                if (grow < M) *(bf16x8*)(Xout + (size_t)grow * 128 + c16 * 8) = v;
            }
            asm volatile("s_waitcnt lgkmcnt(0)" ::: "memory");
        }
    }
}

// ---------- bf16 MFMA flash attention (vectorized V staging; O overwrites Q) ----------
__global__ __launch_bounds__(256, 2) void attn_mfma_kernel(u16* __restrict__ Q,
                                                           const u16* __restrict__ K,
                                                           const u16* __restrict__ V) {
    __shared__ u16 lds_s[64 * 264];
    int b = blockIdx.x >> 1;
    int h = blockIdx.x & 1;
    int tid = threadIdx.x;
    int w = tid >> 6;
    int lane = tid & 63;
    int g = lane >> 4;
    int l15 = lane & 15;

    const u16* Kb = K + ((size_t)b * L) * H + h * HD;
    const u16* Vb = V + ((size_t)b * L) * H + h * HD;
    u16* Qb = Q + ((size_t)b * L) * H + h * HD;

    // V^T staging: bf16x8 global loads (coalesced), scalar LDS scatter.
    // Cols 200..255 get clamped (finite) rows; masked by P=0 in PV.
    {
        int d8 = tid & 7;          // 8 lanes x 16B = 128B contiguous per k-row
        int k8 = tid >> 3;         // 0..31
#pragma unroll
        for (int it = 0; it < 8; ++it) {
            int k = it * 32 + k8;  // 0..255
            bf16x8 v8 = *(const bf16x8*)(Vb + (size_t)min(k, L - 1) * H + d8 * 8);
#pragma unroll
            for (int j = 0; j < 8; ++j)
                lds_s[(d8 * 8 + j) * 264 + k] = v8[j];
        }
    }

    bf16x8 qf[4][2];
    int qrow[4];
#pragma unroll
    for (int nt = 0; nt < 4; ++nt) {
        int q = nt * 64 + w * 16 + l15;
        qrow[nt] = q;
        const u16* src = Qb + (size_t)min(q, L - 1) * H;
        qf[nt][0] = *(const bf16x8*)(src + g * 8);
        qf[nt][1] = *(const bf16x8*)(src + 32 + g * 8);
    }
    __syncthreads();

    f32x4 o[4][4];
    float mrun[4], lrun[4];
#pragma unroll
    for (int i = 0; i < 4; ++i) {
        mrun[i] = -1e30f; lrun[i] = 0.f;
#pragma unroll
        for (int j = 0; j < 4; ++j) o[i][j] = (f32x4){0.f, 0.f, 0.f, 0.f};
    }

    int rp = 8 * (l15 >> 2) + (l15 & 3);
    const f32x4 czero = {0.f, 0.f, 0.f, 0.f};

#pragma unroll
    for (int kc = 0; kc < 4; ++kc) {
        int kbase = kc * 64;
        bf16x8 ka[4][2];
#pragma unroll
        for (int mt = 0; mt < 4; ++mt) {
            int krow = kbase + (mt >> 1) * 32 + (mt & 1) * 4 + rp;
            const u16* src = Kb + (size_t)min(krow, L - 1) * H;
            ka[mt][0] = *(const bf16x8*)(src + g * 8);
            ka[mt][1] = *(const bf16x8*)(src + 32 + g * 8);
        }
#pragma unroll
        for (int nt = 0; nt < 4; ++nt) {
            if (nt < kc) continue;
            int q = qrow[nt];
            f32x4 c[4];
#pragma unroll
            for (int mt = 0; mt < 4; ++mt) {
                c[mt] = MFMA16(ka[mt][0], qf[nt][0], czero, 0, 0, 0);
                c[mt] = MFMA16(ka[mt][1], qf[nt][1], c[mt], 0, 0, 0);
            }
            float pm = -1e30f;
#pragma unroll
            for (int mt = 0; mt < 4; ++mt) {
#pragma unroll
                for (int r = 0; r < 4; ++r) {
                    int kact = kbase + 32 * (mt >> 1) + 4 * (mt & 1) + 8 * g + r;
                    float s = (kact <= q) ? c[mt][r] : -1e30f;
                    c[mt][r] = s;
                    pm = fmaxf(pm, s);
                }
            }
            pm = fmaxf(pm, __shfl_xor(pm, 16));
            pm = fmaxf(pm, __shfl_xor(pm, 32));
            float mnew = fmaxf(mrun[nt], pm);
            float sf = __expf(mrun[nt] - mnew);
            mrun[nt] = mnew;
            float ps = 0.f;
#pragma unroll
            for (int mt = 0; mt < 4; ++mt) {
#pragma unroll
                for (int r = 0; r < 4; ++r) {
                    float p = __expf(c[mt][r] - mnew);
                    c[mt][r] = p;
                    ps += p;
                }
            }
            ps += __shfl_xor(ps, 16);
            ps += __shfl_xor(ps, 32);
            lrun[nt] = lrun[nt] * sf + ps;
#pragma unroll
            for (int md = 0; md < 4; ++md) {
#pragma unroll
                for (int r = 0; r < 4; ++r) o[md][nt][r] *= sf;
            }
#pragma unroll
            for (int ks = 0; ks < 2; ++ks) {
                bf16x8 pb;
#pragma unroll
                for (int j = 0; j < 8; ++j)
                    pb[j] = (short)f2bf(c[2 * ks + (j >> 2)][j & 3]);
#pragma unroll
                for (int md = 0; md < 4; ++md) {
                    const u16* vp = &lds_s[(md * 16 + l15) * 264 + kbase + ks * 32 + g * 8];
                    bf16x8 va = *(const bf16x8*)vp;
                    o[md][nt] = MFMA16(va, pb, o[md][nt], 0, 0, 0);
                }
            }
        }
    }

    __syncthreads();
    u16* Ot = lds_s;
#pragma unroll
    for (int nt = 0; nt < 4; ++nt) {
        float inv = 1.0f / lrun[nt];
        int q = qrow[nt];
        int sw = (q & 7) << 3;
#pragma unroll
        for (int md = 0; md < 4; ++md) {
            int d0 = md * 16 + g * 4;
            unsigned p0 = (unsigned)f2bf(o[md][nt][0] * inv) | ((unsigned)f2bf(o[md][nt][1] * inv) << 16);
            unsigned p1 = (unsigned)f2bf(o[md][nt][2] * inv) | ((unsigned)f2bf(o[md][nt][3] * inv) << 16);
            uint2 u; u.x = p0; u.y = p1;
            *(uint2*)&Ot[q * 64 + (d0 ^ sw)] = u;
        }
    }
    __syncthreads();
    {
        int d = tid & 63;
        for (int q = tid >> 6; q < L; q += 4)
            Qb[(size_t)q * H + d] = Ot[q * 64 + (d ^ ((q & 7) << 3))];
    }
}

extern "C" void kernel_launch(void* const* d_in, const int* in_sizes, int n_in,
                              void* d_out, int out_size, void* d_ws, size_t ws_size,
                              hipStream_t stream) {
    const int* log_seqs = (const int*)d_in[1];
    const int* pos_seqs = (const int*)d_in[2];
    const int* neg_seqs = (const int*)d_in[3];
    const float* item = (const float*)d_in[4];
    const float* post = (const float*)d_in[5];
    const float* qw = (const float*)d_in[6];
    const float* kw = (const float*)d_in[7];
    const float* vw = (const float*)d_in[8];
    const float* ow = (const float*)d_in[9];
    const float* qb = (const float*)d_in[10];
    const float* kb = (const float*)d_in[11];
    const float* vb = (const float*)d_in[12];
    const float* ob = (const float*)d_in[13];
    const float* w1 = (const float*)d_in[14];
    const float* b1 = (const float*)d_in[15];
    const float* w2 = (const float*)d_in[16];
    const float* b2 = (const float*)d_in[17];
    const float* ln1g = (const float*)d_in[18];
    const float* ln1b = (const float*)d_in[19];
    const float* ln2g = (const float*)d_in[20];
    const float* ln2b = (const float*)d_in[21];
    const float* lnfg = (const float*)d_in[22];
    const float* lnfb = (const float*)d_in[23];
    float* out = (float*)d_out;

    int cb = 512;
    while (cb > 8 && (size_t)cb * L * H * 8 + 12 * HH * 2 > ws_size) cb >>= 1;
    size_t nbe = (size_t)cb * L * H;
    u16* X16 = (u16*)d_ws;
    u16* Q16 = X16 + nbe;
    u16* K16 = Q16 + nbe;
    u16* V16 = K16 + nbe;
    u16* w16 = V16 + nbe;

    const float* wsrc[6] = {qw, kw, vw, ow, w1, w2};
    int n8 = NB * HH / 8;
    for (int t = 0; t < 6; ++t)
        cvt_kernel<<<(n8 + 255) / 256, 256, 0, stream>>>(wsrc[t], w16 + (size_t)t * NB * HH, n8);

    for (int b0 = 0; b0 < BTOT; b0 += cb) {
        int M = cb * L;
        int gblk = (M + 127) / 128;
        embed_kernel<<<(M * 16 + 255) / 256, 256, 0, stream>>>(log_seqs + (size_t)b0 * L,
                                                               (const float4*)item, (const float4*)post,
                                                               X16, M);
        for (int i = 0; i < NB; ++i) {
            size_t wo = (size_t)i * HH;
            int bofs = i * H;
            qkv_kernel<<<gblk, 256, 0, stream>>>(X16,
                    w16 + 0 * NB * HH + wo, w16 + 1 * NB * HH + wo, w16 + 2 * NB * HH + wo,
                    qb + bofs, kb + bofs, vb + bofs, Q16, K16, V16, M);
            attn_mfma_kernel<<<cb * 2, 256, 0, stream>>>(Q16, K16, V16);
            oproj_ffn1_kernel<<<gblk, 256, 0, stream>>>(Q16, w16 + 3 * NB * HH + wo, ob + bofs,
                    X16, ln1g + bofs, ln1b + bofs,
                    w16 + 4 * NB * HH + wo, b1 + bofs, X16, K16, M);
            ffn2_ln_kernel<<<gblk, 256, 0, stream>>>(K16, w16 + 5 * NB * HH + wo, b2 + bofs,
                    X16, ln2g + bofs, ln2b + bofs, lnfg, lnfb, (i == NB - 1) ? 1 : 0,
                    X16, item, pos_seqs, neg_seqs, out, b0 * L, M);
        }
    }
}

// Round 11
// 1366.968 us; speedup vs baseline: 1.6851x; 1.2441x over previous
//
#include <hip/hip_runtime.h>
#include <math.h>

#define L 200
#define H 128
#define HD 64
#define NB 2
#define BTOT 2048
#define HH (H * H)
#define XSS 136   // LDS row stride in shorts (272B, 16B-aligned)

typedef short bf16x8 __attribute__((ext_vector_type(8)));
typedef float f32x4 __attribute__((ext_vector_type(4)));
typedef unsigned short u16;

#define MFMA16 __builtin_amdgcn_mfma_f32_16x16x32_bf16

// ---------- helpers ----------
__device__ __forceinline__ u16 f2bf(float f) {
    unsigned u = __builtin_bit_cast(unsigned, f);
    u = u + 0x7fffu + ((u >> 16) & 1u);
    return (u16)(u >> 16);
}
__device__ __forceinline__ float bf2f(u16 s) {
    return __builtin_bit_cast(float, ((unsigned)s) << 16);
}
__device__ __forceinline__ bf16x8 pack8(float4 a, float4 b, float sc) {
    bf16x8 r;
    r[0] = (short)f2bf(a.x * sc); r[1] = (short)f2bf(a.y * sc);
    r[2] = (short)f2bf(a.z * sc); r[3] = (short)f2bf(a.w * sc);
    r[4] = (short)f2bf(b.x * sc); r[5] = (short)f2bf(b.y * sc);
    r[6] = (short)f2bf(b.z * sc); r[7] = (short)f2bf(b.w * sc);
    return r;
}

// ---------- weight f32 -> bf16 ----------
__global__ __launch_bounds__(256) void cvt_kernel(const float* __restrict__ src,
                                                  u16* __restrict__ dst, int n8) {
    int i = blockIdx.x * 256 + threadIdx.x;
    if (i >= n8) return;
    float4 a0 = ((const float4*)src)[i * 2];
    float4 a1 = ((const float4*)src)[i * 2 + 1];
    ((bf16x8*)dst)[i] = pack8(a0, a1, 1.0f);
}

// ---------- embedding (bf16 out) ----------
__global__ __launch_bounds__(256) void embed_kernel(const int* __restrict__ ids,
                                                    const float4* __restrict__ item,
                                                    const float4* __restrict__ post,
                                                    u16* __restrict__ X, int M) {
    int idx = blockIdx.x * 256 + threadIdx.x;
    if (idx >= M * 16) return;
    int r = idx >> 4, c8 = idx & 15;
    int id = ids[r];
    int l = r % L;
    int p = (id != 0) ? (l + 1) : 0;
    float4 a0 = item[(size_t)id * 32 + c8 * 2];
    float4 a1 = item[(size_t)id * 32 + c8 * 2 + 1];
    float4 p0 = post[(size_t)p * 32 + c8 * 2];
    float4 p1 = post[(size_t)p * 32 + c8 * 2 + 1];
    const float sc = 11.313708498984761f;  // sqrt(128)
    float4 o0 = make_float4(a0.x * sc + p0.x, a0.y * sc + p0.y, a0.z * sc + p0.z, a0.w * sc + p0.w);
    float4 o1 = make_float4(a1.x * sc + p1.x, a1.y * sc + p1.y, a1.z * sc + p1.z, a1.w * sc + p1.w);
    *(bf16x8*)&X[(size_t)r * 128 + c8 * 8] = pack8(o0, o1, 1.0f);
}

// ---------- fused QKV (bf16 in/out, Q pre-scaled 0.125) [round-4 verbatim] ----------
__global__ __launch_bounds__(256) void qkv_kernel(const u16* __restrict__ X,
        const u16* __restrict__ wq, const u16* __restrict__ wk, const u16* __restrict__ wv,
        const float* __restrict__ qb, const float* __restrict__ kb, const float* __restrict__ vb,
        u16* __restrict__ Qo, u16* __restrict__ Ko, u16* __restrict__ Vo, int M) {
    __shared__ u16 Xs[128 * XSS];
    __shared__ u16 Ot[4][16 * XSS];
    int tid = threadIdx.x, w = tid >> 6, lane = tid & 63, g = lane >> 4, l15 = lane & 15;
    int row0 = blockIdx.x * 128;
#pragma unroll
    for (int it = 0; it < 8; ++it) {
        int idx = it * 256 + tid;
        int r = idx >> 4, c8 = idx & 15;
        size_t gr = (size_t)min(row0 + r, M - 1);
        *(bf16x8*)&Xs[r * XSS + c8 * 8] = *(const bf16x8*)(X + gr * 128 + c8 * 8);
    }
    __syncthreads();

    int arow = w * 32 + l15;
    int ko = g * 8;

#pragma unroll
    for (int p = 0; p < 3; ++p) {
        const u16* Wp = p == 0 ? wq : (p == 1 ? wk : wv);
        const float* bp = p == 0 ? qb : (p == 1 ? kb : vb);
        u16* Op = p == 0 ? Qo : (p == 1 ? Ko : Vo);
        const float scale = p == 0 ? 0.125f : 1.0f;

        f32x4 acc[2][8];
#pragma unroll
        for (int nt = 0; nt < 8; ++nt) {
            float bv = bp[nt * 16 + l15];
            acc[0][nt] = (f32x4){bv, bv, bv, bv};
            acc[1][nt] = (f32x4){bv, bv, bv, bv};
        }
#pragma unroll
        for (int kc = 0; kc < 4; ++kc) {
            bf16x8 a0 = *(const bf16x8*)&Xs[arow * XSS + kc * 32 + ko];
            bf16x8 a1 = *(const bf16x8*)&Xs[(arow + 16) * XSS + kc * 32 + ko];
#pragma unroll
            for (int nt = 0; nt < 8; ++nt) {
                bf16x8 b = *(const bf16x8*)(Wp + ((size_t)(nt * 16 + l15) << 7) + kc * 32 + ko);
                acc[0][nt] = MFMA16(a0, b, acc[0][nt], 0, 0, 0);
                acc[1][nt] = MFMA16(a1, b, acc[1][nt], 0, 0, 0);
            }
        }
#pragma unroll
        for (int mt = 0; mt < 2; ++mt) {
#pragma unroll
            for (int r = 0; r < 4; ++r) {
                int ml = g * 4 + r;
#pragma unroll
                for (int nt = 0; nt < 8; ++nt)
                    Ot[w][ml * XSS + nt * 16 + l15] = f2bf(acc[mt][nt][r] * scale);
            }
            asm volatile("s_waitcnt lgkmcnt(0)" ::: "memory");
#pragma unroll
            for (int j = 0; j < 4; ++j) {
                int chunk = j * 64 + lane;
                int rr = chunk >> 4, c16 = chunk & 15;
                bf16x8 v = *(const bf16x8*)&Ot[w][rr * XSS + c16 * 8];
                int grow = row0 + w * 32 + mt * 16 + rr;
                if (grow < M) *(bf16x8*)(Op + (size_t)grow * 128 + c16 * 8) = v;
            }
            asm volatile("s_waitcnt lgkmcnt(0)" ::: "memory");
        }
    }
}

// ---------- fused O-proj + residual + LN1 + FFN1 [round-4 verbatim] ----------
__global__ __launch_bounds__(256) void oproj_ffn1_kernel(const u16* __restrict__ A,
        const u16* __restrict__ Wo, const float* __restrict__ ob,
        const u16* __restrict__ Xres, const float* __restrict__ gma, const float* __restrict__ bta,
        const u16* __restrict__ W1, const float* __restrict__ b1f,
        u16* __restrict__ Xout, u16* __restrict__ F1, int M) {
    __shared__ u16 Xs[128 * XSS];
    __shared__ u16 Ot[4][16 * XSS];
    int tid = threadIdx.x, w = tid >> 6, lane = tid & 63, g = lane >> 4, l15 = lane & 15;
    int row0 = blockIdx.x * 128;
    int rw = row0 + w * 32;
    size_t ar0 = (size_t)min(rw + l15, M - 1) * 128;
    size_t ar1 = (size_t)min(rw + 16 + l15, M - 1) * 128;
    int ko = g * 8;

    f32x4 acc[2][8];
#pragma unroll
    for (int nt = 0; nt < 8; ++nt) {
        float bv = ob[nt * 16 + l15];
        acc[0][nt] = (f32x4){bv, bv, bv, bv};
        acc[1][nt] = (f32x4){bv, bv, bv, bv};
    }
#pragma unroll
    for (int kc = 0; kc < 4; ++kc) {
        bf16x8 a0 = *(const bf16x8*)(A + ar0 + kc * 32 + ko);
        bf16x8 a1 = *(const bf16x8*)(A + ar1 + kc * 32 + ko);
#pragma unroll
        for (int nt = 0; nt < 8; ++nt) {
            bf16x8 b = *(const bf16x8*)(Wo + ((size_t)(nt * 16 + l15) << 7) + kc * 32 + ko);
            acc[0][nt] = MFMA16(a0, b, acc[0][nt], 0, 0, 0);
            acc[1][nt] = MFMA16(a1, b, acc[1][nt], 0, 0, 0);
        }
    }
    float gg[8], bb[8];
#pragma unroll
    for (int nt = 0; nt < 8; ++nt) { gg[nt] = gma[nt * 16 + l15]; bb[nt] = bta[nt * 16 + l15]; }
#pragma unroll
    for (int mt = 0; mt < 2; ++mt) {
#pragma unroll
        for (int r = 0; r < 4; ++r) {
            int rowl = w * 32 + mt * 16 + g * 4 + r;
            size_t rb = (size_t)min(row0 + rowl, M - 1) * 128;
            float v[8];
            float s = 0.f;
#pragma unroll
            for (int nt = 0; nt < 8; ++nt) { v[nt] = acc[mt][nt][r] + bf2f(Xres[rb + nt * 16 + l15]); s += v[nt]; }
            s += __shfl_xor(s, 1); s += __shfl_xor(s, 2); s += __shfl_xor(s, 4); s += __shfl_xor(s, 8);
            float mean = s * 0.0078125f;
            float s2 = 0.f;
#pragma unroll
            for (int nt = 0; nt < 8; ++nt) { float d = v[nt] - mean; s2 += d * d; }
            s2 += __shfl_xor(s2, 1); s2 += __shfl_xor(s2, 2); s2 += __shfl_xor(s2, 4); s2 += __shfl_xor(s2, 8);
            float inv = rsqrtf(s2 * 0.0078125f + 1e-8f);
#pragma unroll
            for (int nt = 0; nt < 8; ++nt)
                Xs[rowl * XSS + nt * 16 + l15] = f2bf((v[nt] - mean) * inv * gg[nt] + bb[nt]);
        }
    }
    __syncthreads();

#pragma unroll
    for (int it = 0; it < 8; ++it) {
        int idx = it * 256 + tid;
        int r = idx >> 4, c8 = idx & 15;
        int grow = row0 + r;
        if (grow < M)
            *(bf16x8*)(Xout + (size_t)grow * 128 + c8 * 8) = *(const bf16x8*)&Xs[r * XSS + c8 * 8];
    }

    int arow = w * 32 + l15;
    f32x4 acc2[2][8];
#pragma unroll
    for (int nt = 0; nt < 8; ++nt) {
        float bv = b1f[nt * 16 + l15];
        acc2[0][nt] = (f32x4){bv, bv, bv, bv};
        acc2[1][nt] = (f32x4){bv, bv, bv, bv};
    }
#pragma unroll
    for (int kc = 0; kc < 4; ++kc) {
        bf16x8 a0 = *(const bf16x8*)&Xs[arow * XSS + kc * 32 + ko];
        bf16x8 a1 = *(const bf16x8*)&Xs[(arow + 16) * XSS + kc * 32 + ko];
#pragma unroll
        for (int nt = 0; nt < 8; ++nt) {
            bf16x8 b = *(const bf16x8*)(W1 + ((size_t)(nt * 16 + l15) << 7) + kc * 32 + ko);
            acc2[0][nt] = MFMA16(a0, b, acc2[0][nt], 0, 0, 0);
            acc2[1][nt] = MFMA16(a1, b, acc2[1][nt], 0, 0, 0);
        }
    }
#pragma unroll
    for (int mt = 0; mt < 2; ++mt) {
#pragma unroll
        for (int r = 0; r < 4; ++r) {
            int ml = g * 4 + r;
#pragma unroll
            for (int nt = 0; nt < 8; ++nt)
                Ot[w][ml * XSS + nt * 16 + l15] = f2bf(fmaxf(acc2[mt][nt][r], 0.f));
        }
        asm volatile("s_waitcnt lgkmcnt(0)" ::: "memory");
#pragma unroll
        for (int j = 0; j < 4; ++j) {
            int chunk = j * 64 + lane;
            int rr = chunk >> 4, c16 = chunk & 15;
            bf16x8 v = *(const bf16x8*)&Ot[w][rr * XSS + c16 * 8];
            int grow = row0 + w * 32 + mt * 16 + rr;
            if (grow < M) *(bf16x8*)(F1 + (size_t)grow * 128 + c16 * 8) = v;
        }
        asm volatile("s_waitcnt lgkmcnt(0)" ::: "memory");
    }
}

// ---------- FFN2 + residual + LN2 (+ final LN + logits when fin) [round-4 verbatim] ----------
__global__ __launch_bounds__(256) void ffn2_ln_kernel(const u16* __restrict__ A,
        const u16* __restrict__ W2, const float* __restrict__ bias,
        const u16* __restrict__ Xres, const float* __restrict__ gma, const float* __restrict__ bta,
        const float* __restrict__ gf, const float* __restrict__ bff, int fin,
        u16* __restrict__ Xout, const float* __restrict__ item,
        const int* __restrict__ pid, const int* __restrict__ nid,
        float* __restrict__ out, int gofs, int M) {
    __shared__ u16 Ot[4][16 * XSS];
    int tid = threadIdx.x, w = tid >> 6, lane = tid & 63, g = lane >> 4, l15 = lane & 15;
    int row0 = blockIdx.x * 128;
    int rw = row0 + w * 32;
    size_t ar0 = (size_t)min(rw + l15, M - 1) * 128;
    size_t ar1 = (size_t)min(rw + 16 + l15, M - 1) * 128;
    int ko = g * 8;

    f32x4 acc[2][8];
#pragma unroll
    for (int nt = 0; nt < 8; ++nt) {
        float bv = bias[nt * 16 + l15];
        acc[0][nt] = (f32x4){bv, bv, bv, bv};
        acc[1][nt] = (f32x4){bv, bv, bv, bv};
    }
#pragma unroll
    for (int kc = 0; kc < 4; ++kc) {
        bf16x8 a0 = *(const bf16x8*)(A + ar0 + kc * 32 + ko);
        bf16x8 a1 = *(const bf16x8*)(A + ar1 + kc * 32 + ko);
#pragma unroll
        for (int nt = 0; nt < 8; ++nt) {
            bf16x8 b = *(const bf16x8*)(W2 + ((size_t)(nt * 16 + l15) << 7) + kc * 32 + ko);
            acc[0][nt] = MFMA16(a0, b, acc[0][nt], 0, 0, 0);
            acc[1][nt] = MFMA16(a1, b, acc[1][nt], 0, 0, 0);
        }
    }
    float gg[8], bb[8], gg2[8], bb2[8];
#pragma unroll
    for (int nt = 0; nt < 8; ++nt) {
        gg[nt] = gma[nt * 16 + l15]; bb[nt] = bta[nt * 16 + l15];
        gg2[nt] = gf[nt * 16 + l15]; bb2[nt] = bff[nt * 16 + l15];
    }
#pragma unroll
    for (int mt = 0; mt < 2; ++mt) {
#pragma unroll
        for (int r = 0; r < 4; ++r) {
            int row = row0 + w * 32 + mt * 16 + g * 4 + r;
            size_t rb = (size_t)min(row, M - 1) * 128;
            float v[8];
            float s = 0.f;
#pragma unroll
            for (int nt = 0; nt < 8; ++nt) { v[nt] = acc[mt][nt][r] + bf2f(Xres[rb + nt * 16 + l15]); s += v[nt]; }
            s += __shfl_xor(s, 1); s += __shfl_xor(s, 2); s += __shfl_xor(s, 4); s += __shfl_xor(s, 8);
            float mean = s * 0.0078125f;
            float s2 = 0.f;
#pragma unroll
            for (int nt = 0; nt < 8; ++nt) { float d = v[nt] - mean; s2 += d * d; }
            s2 += __shfl_xor(s2, 1); s2 += __shfl_xor(s2, 2); s2 += __shfl_xor(s2, 4); s2 += __shfl_xor(s2, 8);
            float inv = rsqrtf(s2 * 0.0078125f + 1e-8f);
#pragma unroll
            for (int nt = 0; nt < 8; ++nt) v[nt] = (v[nt] - mean) * inv * gg[nt] + bb[nt];
            if (fin) {
                float t = 0.f;
#pragma unroll
                for (int nt = 0; nt < 8; ++nt) t += v[nt];
                t += __shfl_xor(t, 1); t += __shfl_xor(t, 2); t += __shfl_xor(t, 4); t += __shfl_xor(t, 8);
                float mean2 = t * 0.0078125f;
                float t2 = 0.f;
#pragma unroll
                for (int nt = 0; nt < 8; ++nt) { float d = v[nt] - mean2; t2 += d * d; }
                t2 += __shfl_xor(t2, 1); t2 += __shfl_xor(t2, 2); t2 += __shfl_xor(t2, 4); t2 += __shfl_xor(t2, 8);
                float inv2 = rsqrtf(t2 * 0.0078125f + 1e-8f);
#pragma unroll
                for (int nt = 0; nt < 8; ++nt) v[nt] = (v[nt] - mean2) * inv2 * gg2[nt] + bb2[nt];
                int gr = gofs + row;
                const float* prow = item + (size_t)pid[gr] * 128;
                const float* nrow = item + (size_t)nid[gr] * 128;
                float sp = 0.f, sn = 0.f;
#pragma unroll
                for (int nt = 0; nt < 8; ++nt) {
                    sp += v[nt] * prow[nt * 16 + l15];
                    sn += v[nt] * nrow[nt * 16 + l15];
                }
                sp += __shfl_xor(sp, 1); sp += __shfl_xor(sp, 2); sp += __shfl_xor(sp, 4); sp += __shfl_xor(sp, 8);
                sn += __shfl_xor(sn, 1); sn += __shfl_xor(sn, 2); sn += __shfl_xor(sn, 4); sn += __shfl_xor(sn, 8);
                if (l15 == 0 && row < M) {
                    out[gr] = sp;
                    out[(size_t)BTOT * L + gr] = sn;
                }
            } else {
                int ml = g * 4 + r;
#pragma unroll
                for (int nt = 0; nt < 8; ++nt)
                    Ot[w][ml * XSS + nt * 16 + l15] = f2bf(v[nt]);
            }
        }
        if (!fin) {
            asm volatile("s_waitcnt lgkmcnt(0)" ::: "memory");
#pragma unroll
            for (int j = 0; j < 4; ++j) {
                int chunk = j * 64 + lane;
                int rr = chunk >> 4, c16 = chunk & 15;
                bf16x8 v = *(const bf16x8*)&Ot[w][rr * XSS + c16 * 8];
                int grow = row0 + w * 32 + mt * 16 + rr;
                if (grow < M) *(bf16x8*)(Xout + (size_t)grow * 128 + c16 * 8) = v;
            }
            asm volatile("s_waitcnt lgkmcnt(0)" ::: "memory");
        }
    }
}

// ---------- bf16 MFMA flash attention [round-4 verbatim] ----------
__global__ __launch_bounds__(256, 2) void attn_mfma_kernel(u16* __restrict__ Q,
                                                           const u16* __restrict__ K,
                                                           const u16* __restrict__ V) {
    __shared__ u16 lds_s[64 * 264];
    int b = blockIdx.x >> 1;
    int h = blockIdx.x & 1;
    int tid = threadIdx.x;
    int w = tid >> 6;
    int lane = tid & 63;
    int g = lane >> 4;
    int l15 = lane & 15;

    const u16* Kb = K + ((size_t)b * L) * H + h * HD;
    const u16* Vb = V + ((size_t)b * L) * H + h * HD;
    u16* Qb = Q + ((size_t)b * L) * H + h * HD;

    {
        int d = tid & 63;
        int kq = tid >> 6;
#pragma unroll 8
        for (int it = 0; it < 64; ++it) {
            int k = it * 4 + kq;
            lds_s[d * 264 + k] = Vb[(size_t)min(k, L - 1) * H + d];
        }
    }

    bf16x8 qf[4][2];
    int qrow[4];
#pragma unroll
    for (int nt = 0; nt < 4; ++nt) {
        int q = nt * 64 + w * 16 + l15;
        qrow[nt] = q;
        const u16* src = Qb + (size_t)min(q, L - 1) * H;
        qf[nt][0] = *(const bf16x8*)(src + g * 8);
        qf[nt][1] = *(const bf16x8*)(src + 32 + g * 8);
    }
    __syncthreads();

    f32x4 o[4][4];
    float mrun[4], lrun[4];
#pragma unroll
    for (int i = 0; i < 4; ++i) {
        mrun[i] = -1e30f; lrun[i] = 0.f;
#pragma unroll
        for (int j = 0; j < 4; ++j) o[i][j] = (f32x4){0.f, 0.f, 0.f, 0.f};
    }

    int rp = 8 * (l15 >> 2) + (l15 & 3);
    const f32x4 czero = {0.f, 0.f, 0.f, 0.f};

#pragma unroll
    for (int kc = 0; kc < 4; ++kc) {
        int kbase = kc * 64;
        bf16x8 ka[4][2];
#pragma unroll
        for (int mt = 0; mt < 4; ++mt) {
            int krow = kbase + (mt >> 1) * 32 + (mt & 1) * 4 + rp;
            const u16* src = Kb + (size_t)min(krow, L - 1) * H;
            ka[mt][0] = *(const bf16x8*)(src + g * 8);
            ka[mt][1] = *(const bf16x8*)(src + 32 + g * 8);
        }
#pragma unroll
        for (int nt = 0; nt < 4; ++nt) {
            if (nt < kc) continue;
            int q = qrow[nt];
            f32x4 c[4];
#pragma unroll
            for (int mt = 0; mt < 4; ++mt) {
                c[mt] = MFMA16(ka[mt][0], qf[nt][0], czero, 0, 0, 0);
                c[mt] = MFMA16(ka[mt][1], qf[nt][1], c[mt], 0, 0, 0);
            }
            float pm = -1e30f;
#pragma unroll
            for (int mt = 0; mt < 4; ++mt) {
#pragma unroll
                for (int r = 0; r < 4; ++r) {
                    int kact = kbase + 32 * (mt >> 1) + 4 * (mt & 1) + 8 * g + r;
                    float s = (kact <= q) ? c[mt][r] : -1e30f;
                    c[mt][r] = s;
                    pm = fmaxf(pm, s);
                }
            }
            pm = fmaxf(pm, __shfl_xor(pm, 16));
            pm = fmaxf(pm, __shfl_xor(pm, 32));
            float mnew = fmaxf(mrun[nt], pm);
            float sf = __expf(mrun[nt] - mnew);
            mrun[nt] = mnew;
            float ps = 0.f;
#pragma unroll
            for (int mt = 0; mt < 4; ++mt) {
#pragma unroll
                for (int r = 0; r < 4; ++r) {
                    float p = __expf(c[mt][r] - mnew);
                    c[mt][r] = p;
                    ps += p;
                }
            }
            ps += __shfl_xor(ps, 16);
            ps += __shfl_xor(ps, 32);
            lrun[nt] = lrun[nt] * sf + ps;
#pragma unroll
            for (int md = 0; md < 4; ++md) {
#pragma unroll
                for (int r = 0; r < 4; ++r) o[md][nt][r] *= sf;
            }
#pragma unroll
            for (int ks = 0; ks < 2; ++ks) {
                bf16x8 pb;
#pragma unroll
                for (int j = 0; j < 8; ++j)
                    pb[j] = (short)f2bf(c[2 * ks + (j >> 2)][j & 3]);
#pragma unroll
                for (int md = 0; md < 4; ++md) {
                    const u16* vp = &lds_s[(md * 16 + l15) * 264 + kbase + ks * 32 + g * 8];
                    bf16x8 va = *(const bf16x8*)vp;
                    o[md][nt] = MFMA16(va, pb, o[md][nt], 0, 0, 0);
                }
            }
        }
    }

    __syncthreads();
    u16* Ot = lds_s;
#pragma unroll
    for (int nt = 0; nt < 4; ++nt) {
        float inv = 1.0f / lrun[nt];
        int q = qrow[nt];
        int sw = (q & 7) << 3;
#pragma unroll
        for (int md = 0; md < 4; ++md) {
            int d0 = md * 16 + g * 4;
            unsigned p0 = (unsigned)f2bf(o[md][nt][0] * inv) | ((unsigned)f2bf(o[md][nt][1] * inv) << 16);
            unsigned p1 = (unsigned)f2bf(o[md][nt][2] * inv) | ((unsigned)f2bf(o[md][nt][3] * inv) << 16);
            uint2 u; u.x = p0; u.y = p1;
            *(uint2*)&Ot[q * 64 + (d0 ^ sw)] = u;
        }
    }
    __syncthreads();
    {
        int d = tid & 63;
        for (int q = tid >> 6; q < L; q += 4)
            Qb[(size_t)q * H + d] = Ot[q * 64 + (d ^ ((q & 7) << 3))];
    }
}

extern "C" void kernel_launch(void* const* d_in, const int* in_sizes, int n_in,
                              void* d_out, int out_size, void* d_ws, size_t ws_size,
                              hipStream_t stream) {
    const int* log_seqs = (const int*)d_in[1];
    const int* pos_seqs = (const int*)d_in[2];
    const int* neg_seqs = (const int*)d_in[3];
    const float* item = (const float*)d_in[4];
    const float* post = (const float*)d_in[5];
    const float* qw = (const float*)d_in[6];
    const float* kw = (const float*)d_in[7];
    const float* vw = (const float*)d_in[8];
    const float* ow = (const float*)d_in[9];
    const float* qb = (const float*)d_in[10];
    const float* kb = (const float*)d_in[11];
    const float* vb = (const float*)d_in[12];
    const float* ob = (const float*)d_in[13];
    const float* w1 = (const float*)d_in[14];
    const float* b1 = (const float*)d_in[15];
    const float* w2 = (const float*)d_in[16];
    const float* b2 = (const float*)d_in[17];
    const float* ln1g = (const float*)d_in[18];
    const float* ln1b = (const float*)d_in[19];
    const float* ln2g = (const float*)d_in[20];
    const float* ln2b = (const float*)d_in[21];
    const float* lnfg = (const float*)d_in[22];
    const float* lnfb = (const float*)d_in[23];
    float* out = (float*)d_out;

    // single chunk: 15 dispatches total (vs 42 at cb=512)
    int cb = BTOT;
    while (cb > 8 && (size_t)cb * L * H * 8 + 12 * HH * 2 > ws_size) cb >>= 1;
    size_t nbe = (size_t)cb * L * H;
    u16* X16 = (u16*)d_ws;
    u16* Q16 = X16 + nbe;
    u16* K16 = Q16 + nbe;
    u16* V16 = K16 + nbe;
    u16* w16 = V16 + nbe;

    const float* wsrc[6] = {qw, kw, vw, ow, w1, w2};
    int n8 = NB * HH / 8;
    for (int t = 0; t < 6; ++t)
        cvt_kernel<<<(n8 + 255) / 256, 256, 0, stream>>>(wsrc[t], w16 + (size_t)t * NB * HH, n8);

    for (int b0 = 0; b0 < BTOT; b0 += cb) {
        int M = cb * L;
        int gblk = (M + 127) / 128;
        embed_kernel<<<(M * 16 + 255) / 256, 256, 0, stream>>>(log_seqs + (size_t)b0 * L,
                                                               (const float4*)item, (const float4*)post,
                                                               X16, M);
        for (int i = 0; i < NB; ++i) {
            size_t wo = (size_t)i * HH;
            int bofs = i * H;
            qkv_kernel<<<gblk, 256, 0, stream>>>(X16,
                    w16 + 0 * NB * HH + wo, w16 + 1 * NB * HH + wo, w16 + 2 * NB * HH + wo,
                    qb + bofs, kb + bofs, vb + bofs, Q16, K16, V16, M);
            attn_mfma_kernel<<<cb * 2, 256, 0, stream>>>(Q16, K16, V16);
            oproj_ffn1_kernel<<<gblk, 256, 0, stream>>>(Q16, w16 + 3 * NB * HH + wo, ob + bofs,
                    X16, ln1g + bofs, ln1b + bofs,
                    w16 + 4 * NB * HH + wo, b1 + bofs, X16, K16, M);
            ffn2_ln_kernel<<<gblk, 256, 0, stream>>>(K16, w16 + 5 * NB * HH + wo, b2 + bofs,
                    X16, ln2g + bofs, ln2b + bofs, lnfg, lnfb, (i == NB - 1) ? 1 : 0,
                    X16, item, pos_seqs, neg_seqs, out, b0 * L, M);
        }
    }
}